// Round 1
// baseline (482.357 us; speedup 1.0000x reference)
//
#include <hip/hip_runtime.h>
#include <math.h>

#define B_ 8
#define C_ 64
#define T_ 1200
#define SPLITK 4

#ifndef M_PI
#define M_PI 3.14159265358979323846
#endif

union F4 { float4 v; float f[4]; };

// ---------------- mask detect + convert to float ----------------
// Harness may pass bool as 1-byte, as int32, or as float. Detect by scanning
// the first n/4 32-bit words (valid memory in all layouts).
__global__ void mask_convert_kernel(const void* __restrict__ mask_raw,
                                    float* __restrict__ mf, int n) {
    __shared__ int s_bad_int, s_bad_flt;
    if (threadIdx.x == 0) { s_bad_int = 0; s_bad_flt = 0; }
    __syncthreads();
    const unsigned int* wi = (const unsigned int*)mask_raw;
    const float* wf = (const float*)mask_raw;
    int nw = n >> 2;
    int badI = 0, badF = 0;
    for (int i = threadIdx.x; i < nw; i += blockDim.x) {
        unsigned int v = wi[i];
        if (v > 1u) badI = 1;
        float f = wf[i];
        if (!(f == 0.0f || f == 1.0f)) badF = 1;
    }
    if (badI) s_bad_int = 1;
    if (badF) s_bad_flt = 1;
    __syncthreads();
    int mode = (!s_bad_int) ? 0 : ((!s_bad_flt) ? 1 : 2);
    for (int i = threadIdx.x; i < n; i += blockDim.x) {
        float v;
        if (mode == 0)      v = (float)((const int*)mask_raw)[i];
        else if (mode == 1) v = ((const float*)mask_raw)[i];
        else                v = (float)((const unsigned char*)mask_raw)[i];
        mf[i] = v;
    }
}

__global__ void cnt_kernel(const float* __restrict__ mf, float* __restrict__ cnt) {
    __shared__ float red[256];
    int b = blockIdx.x;
    float s = 0.f;
    for (int t = threadIdx.x; t < T_; t += 256) s += mf[b * T_ + t];
    red[threadIdx.x] = s; __syncthreads();
    for (int w = 128; w > 0; w >>= 1) {
        if (threadIdx.x < w) red[threadIdx.x] += red[threadIdx.x + w];
        __syncthreads();
    }
    if (threadIdx.x == 0) cnt[b] = red[0];
}

// ---------------- basis: C[k,t]=cos(w_k * t), S[k,t]=sin(w_k * t) ----------------
// omega replicated from numpy: float32(2*pi*(fstep + k*fstep)); arg in double.
__global__ void basis_kernel(float* __restrict__ Cb, float* __restrict__ Sb, double fstep) {
    int k = blockIdx.x;
    double om = 2.0 * M_PI * (fstep + (double)k * fstep);
    float om_f = (float)om;
    double w = (double)om_f;
    for (int t = threadIdx.x; t < T_; t += blockDim.x) {
        double s, c;
        sincos(w * (double)(t + 1), &s, &c);
        Cb[(size_t)k * T_ + t] = (float)c;
        Sb[(size_t)k * T_ + t] = (float)s;
    }
}

// ---------------- tau sums + phase + denominators ----------------
// sin(2wt)=2SC, cos(2wt)=(C-S)(C+S);  A=Sum m*C^2=(cnt+C2)/2, D=(cnt-C2)/2, E=S2/2
__global__ void tau_kernel(const float* __restrict__ Cb, const float* __restrict__ Sb,
                           const float* __restrict__ mf, const float* __restrict__ cnt,
                           float* __restrict__ cphi, float* __restrict__ sphi,
                           float* __restrict__ denc, float* __restrict__ dens, int K) {
    int k = blockIdx.x;
    int lane = threadIdx.x; // 64
    float s2[B_], c2[B_];
#pragma unroll
    for (int b = 0; b < B_; b++) { s2[b] = 0.f; c2[b] = 0.f; }
    for (int t = lane; t < T_; t += 64) {
        float c = Cb[(size_t)k * T_ + t];
        float s = Sb[(size_t)k * T_ + t];
        float sin2 = 2.0f * s * c;
        float cos2 = (c - s) * (c + s);
#pragma unroll
        for (int b = 0; b < B_; b++) {
            float m = mf[b * T_ + t];
            s2[b] = fmaf(m, sin2, s2[b]);
            c2[b] = fmaf(m, cos2, c2[b]);
        }
    }
#pragma unroll
    for (int b = 0; b < B_; b++) {
#pragma unroll
        for (int off = 32; off > 0; off >>= 1) {
            s2[b] += __shfl_xor(s2[b], off, 64);
            c2[b] += __shfl_xor(c2[b], off, 64);
        }
    }
    if (lane == 0) {
#pragma unroll
        for (int b = 0; b < B_; b++) {
            float S2v = s2[b], C2v = c2[b];
            float phi = 0.5f * atan2f(S2v, C2v);
            float cp = cosf(phi), sp = sinf(phi);
            float cn = cnt[b];
            float A = 0.5f * (cn + C2v), D = 0.5f * (cn - C2v), E = 0.5f * S2v;
            cphi[b * K + k] = cp;
            sphi[b * K + k] = sp;
            denc[b * K + k] = cp * cp * A + 2.f * cp * sp * E + sp * sp * D;
            dens[b * K + k] = sp * sp * A - 2.f * cp * sp * E + cp * cp * D;
        }
    }
}

// ---------------- GEMM1: P[b,k,c]=Sum_t C[k,t]*dm[b,c,t]; Q with S ----------------
// block: 64 k x 64 c, T-chunks of 16. dm folded in via mf on load.
__global__ __launch_bounds__(256) void gemm1_kernel(
    const float* __restrict__ Cb, const float* __restrict__ Sb,
    const float* __restrict__ data, const float* __restrict__ mf,
    float* __restrict__ P, float* __restrict__ Q, int K) {
    __shared__ float sC[16][68], sS[16][68], sD[16][68];
    int b = blockIdx.y;
    int k0 = blockIdx.x * 64;
    int tid = threadIdx.x;
    int lr = tid >> 2;          // 0..63 load row
    int lj = (tid & 3) * 4;     // 0,4,8,12 col offset
    int ty = tid >> 4;          // k quad
    int tx = tid & 15;          // c quad
    float pa[4][4] = {{0}}, qa[4][4] = {{0}};
    for (int tt = 0; tt < T_; tt += 16) {
        int krow = k0 + lr;
        F4 cv, sv, dv;
        cv.v = make_float4(0, 0, 0, 0); sv.v = cv.v;
        if (krow < K) {
            cv.v = *(const float4*)&Cb[(size_t)krow * T_ + tt + lj];
            sv.v = *(const float4*)&Sb[(size_t)krow * T_ + tt + lj];
        }
        dv.v = *(const float4*)&data[((size_t)b * C_ + lr) * T_ + tt + lj];
        float mw[4];
#pragma unroll
        for (int e = 0; e < 4; e++) mw[e] = mf[b * T_ + tt + lj + e];
        __syncthreads();
#pragma unroll
        for (int e = 0; e < 4; e++) {
            sC[lj + e][lr] = cv.f[e];
            sS[lj + e][lr] = sv.f[e];
            sD[lj + e][lr] = dv.f[e] * mw[e];
        }
        __syncthreads();
#pragma unroll
        for (int t = 0; t < 16; t++) {
            F4 a, e4, d;
            a.v = *(const float4*)&sC[t][ty * 4];
            e4.v = *(const float4*)&sS[t][ty * 4];
            d.v = *(const float4*)&sD[t][tx * 4];
#pragma unroll
            for (int i = 0; i < 4; i++)
#pragma unroll
                for (int j = 0; j < 4; j++) {
                    pa[i][j] = fmaf(a.f[i], d.f[j], pa[i][j]);
                    qa[i][j] = fmaf(e4.f[i], d.f[j], qa[i][j]);
                }
        }
    }
#pragma unroll
    for (int i = 0; i < 4; i++) {
        int kk = k0 + ty * 4 + i;
        if (kk < K) {
            F4 pv, qv;
#pragma unroll
            for (int j = 0; j < 4; j++) { pv.f[j] = pa[i][j]; qv.f[j] = qa[i][j]; }
            *(float4*)&P[((size_t)b * K + kk) * C_ + tx * 4] = pv.v;
            *(float4*)&Q[((size_t)b * K + kk) * C_ + tx * 4] = qv.v;
        }
    }
}

// ---------------- combine: coef fit + rotate back to (U,V) in place ----------------
__global__ void combine_kernel(float* __restrict__ P, float* __restrict__ Q,
                               const float* __restrict__ cphi, const float* __restrict__ sphi,
                               const float* __restrict__ denc, const float* __restrict__ dens,
                               int K) {
    long long idx = (long long)blockIdx.x * 256 + threadIdx.x;
    long long total = (long long)B_ * K * C_;
    if (idx >= total) return;
    long long bk = idx >> 6; // /C_
    int k = (int)(bk % K);
    int b = (int)(bk / K);
    float cp = cphi[b * K + k], sp = sphi[b * K + k];
    float dc = denc[b * K + k], ds = dens[b * K + k];
    float p = P[idx], q = Q[idx];
    float ccoef = (cp * p + sp * q) / dc;
    float scoef = (cp * q - sp * p) / ds;
    P[idx] = cp * ccoef - sp * scoef;  // U
    Q[idx] = sp * ccoef + cp * scoef;  // V
}

// ---------------- GEMM2: recon[b,c,t] = Sum_k U*C + V*S (split-K partials) ----------------
__global__ __launch_bounds__(256) void gemm2_kernel(
    const float* __restrict__ Cb, const float* __restrict__ Sb,
    const float* __restrict__ U, const float* __restrict__ V,
    float* __restrict__ rpart, int K) {
    __shared__ float sU[16][68], sV[16][68], sCc[16][68], sSc[16][68];
    int b = blockIdx.y;
    int t0 = blockIdx.x * 64;
    int sk = blockIdx.z;
    int kbeg = (int)(((long long)K * sk) / SPLITK);
    int kend = (int)(((long long)K * (sk + 1)) / SPLITK);
    int tid = threadIdx.x;
    int kk = tid >> 4;         // 0..15 load row
    int j4 = (tid & 15) * 4;   // load col*4
    int ty = tid >> 4;         // c quad
    int tx = tid & 15;         // t quad
    float acc[4][4] = {{0}};
    for (int kc = kbeg; kc < kend; kc += 16) {
        int krow = kc + kk;
        F4 uv, vv, cc, ss;
        uv.v = make_float4(0, 0, 0, 0); vv.v = uv.v; cc.v = uv.v; ss.v = uv.v;
        if (krow < kend) {
            uv.v = *(const float4*)&U[((size_t)b * K + krow) * C_ + j4];
            vv.v = *(const float4*)&V[((size_t)b * K + krow) * C_ + j4];
#pragma unroll
            for (int e = 0; e < 4; e++) {
                int t = t0 + j4 + e;
                if (t < T_) {
                    cc.f[e] = Cb[(size_t)krow * T_ + t];
                    ss.f[e] = Sb[(size_t)krow * T_ + t];
                }
            }
        }
        __syncthreads();
        *(float4*)&sU[kk][j4] = uv.v;
        *(float4*)&sV[kk][j4] = vv.v;
        *(float4*)&sCc[kk][j4] = cc.v;
        *(float4*)&sSc[kk][j4] = ss.v;
        __syncthreads();
#pragma unroll
        for (int k = 0; k < 16; k++) {
            F4 u, v, cb4, sb4;
            u.v = *(const float4*)&sU[k][ty * 4];
            v.v = *(const float4*)&sV[k][ty * 4];
            cb4.v = *(const float4*)&sCc[k][tx * 4];
            sb4.v = *(const float4*)&sSc[k][tx * 4];
#pragma unroll
            for (int i = 0; i < 4; i++)
#pragma unroll
                for (int j = 0; j < 4; j++) {
                    acc[i][j] = fmaf(u.f[i], cb4.f[j], acc[i][j]);
                    acc[i][j] = fmaf(v.f[i], sb4.f[j], acc[i][j]);
                }
        }
    }
    float* rp = rpart + (size_t)sk * B_ * C_ * T_;
#pragma unroll
    for (int i = 0; i < 4; i++) {
        int c = ty * 4 + i;
#pragma unroll
        for (int j = 0; j < 4; j++) {
            int t = t0 + tx * 4 + j;
            if (t < T_) rp[((size_t)b * C_ + c) * T_ + t] = acc[i][j];
        }
    }
}

// ---------------- normalize + select ----------------
__global__ void norm_kernel(const float* __restrict__ rpart, const float* __restrict__ data,
                            const float* __restrict__ mf, const float* __restrict__ cnt,
                            float* __restrict__ out) {
    __shared__ float red[256];
    __shared__ float s_meanr, s_mu, s_scale;
    int bc = blockIdx.x;
    int b = bc >> 6; // / C_
    const size_t base = (size_t)bc * T_;
    const size_t stride = (size_t)B_ * C_ * T_;
    float sr = 0.f, sd = 0.f;
    for (int t = threadIdx.x; t < T_; t += 256) {
        float r = rpart[base + t] + rpart[stride + base + t]
                + rpart[2 * stride + base + t] + rpart[3 * stride + base + t];
        sr += r;
        sd += data[base + t] * mf[b * T_ + t];
    }
    red[threadIdx.x] = sr; __syncthreads();
    for (int w = 128; w > 0; w >>= 1) { if (threadIdx.x < w) red[threadIdx.x] += red[threadIdx.x + w]; __syncthreads(); }
    if (threadIdx.x == 0) s_meanr = red[0] / (float)T_;
    __syncthreads();
    red[threadIdx.x] = sd; __syncthreads();
    for (int w = 128; w > 0; w >>= 1) { if (threadIdx.x < w) red[threadIdx.x] += red[threadIdx.x + w]; __syncthreads(); }
    if (threadIdx.x == 0) s_mu = red[0] / cnt[b];
    __syncthreads();
    float meanr = s_meanr, mu = s_mu;
    float vr = 0.f, vd = 0.f;
    for (int t = threadIdx.x; t < T_; t += 256) {
        float r = rpart[base + t] + rpart[stride + base + t]
                + rpart[2 * stride + base + t] + rpart[3 * stride + base + t];
        float dr = r - meanr; vr += dr * dr;
        float x = data[base + t];
        float m = mf[b * T_ + t];
        float dx = x - mu; vd += dx * dx * m;
    }
    red[threadIdx.x] = vr; __syncthreads();
    for (int w = 128; w > 0; w >>= 1) { if (threadIdx.x < w) red[threadIdx.x] += red[threadIdx.x + w]; __syncthreads(); }
    float varr = red[0];
    __syncthreads();
    red[threadIdx.x] = vd; __syncthreads();
    for (int w = 128; w > 0; w >>= 1) { if (threadIdx.x < w) red[threadIdx.x] += red[threadIdx.x + w]; __syncthreads(); }
    if (threadIdx.x == 0) {
        float sdr = sqrtf(varr / (float)(T_ - 1));
        float sdo = sqrtf(red[0] / (cnt[b] - 1.0f));
        s_scale = sdo / sdr;
    }
    __syncthreads();
    float scale = s_scale;
    for (int t = threadIdx.x; t < T_; t += 256) {
        float r = rpart[base + t] + rpart[stride + base + t]
                + rpart[2 * stride + base + t] + rpart[3 * stride + base + t];
        float m = mf[b * T_ + t];
        out[base + t] = (m > 0.5f) ? data[base + t] : r * scale;
    }
}

extern "C" void kernel_launch(void* const* d_in, const int* in_sizes, int n_in,
                              void* d_out, int out_size, void* d_ws, size_t ws_size,
                              hipStream_t stream) {
    const float* data = (const float*)d_in[0];
    const void* mask = d_in[1];
    float* out = (float*)d_out;

    // Replicate numpy arange length computation exactly (double precision).
    const double timespan = 1.0 * (T_ + 1) - 1.0;               // 1200
    const double fstep = 1.0 / (timespan * 8.0);                // OSFREQ = 8
    const double stop = (1.0 * (double)T_) / (2.0 * timespan) + fstep;
    const int K = (int)ceil((stop - fstep) / fstep);            // expected 4800

    char* w = (char*)d_ws;
    auto alloc = [&](size_t nfloats) {
        float* p = (float*)w;
        w += ((nfloats * sizeof(float) + 255) / 256) * 256;
        return p;
    };
    float* mf    = alloc((size_t)B_ * T_);
    float* cnt   = alloc(B_);
    float* Cb    = alloc((size_t)K * T_);
    float* Sb    = alloc((size_t)K * T_);
    float* cphi  = alloc((size_t)B_ * K);
    float* sphi  = alloc((size_t)B_ * K);
    float* denc  = alloc((size_t)B_ * K);
    float* dens  = alloc((size_t)B_ * K);
    float* P     = alloc((size_t)B_ * K * C_);
    float* Q     = alloc((size_t)B_ * K * C_);
    float* rpart = alloc((size_t)SPLITK * B_ * C_ * T_);
    (void)ws_size; (void)in_sizes; (void)n_in; (void)out_size;

    mask_convert_kernel<<<1, 256, 0, stream>>>(mask, mf, B_ * T_);
    cnt_kernel<<<B_, 256, 0, stream>>>(mf, cnt);
    basis_kernel<<<K, 256, 0, stream>>>(Cb, Sb, fstep);
    tau_kernel<<<K, 64, 0, stream>>>(Cb, Sb, mf, cnt, cphi, sphi, denc, dens, K);
    gemm1_kernel<<<dim3((K + 63) / 64, B_), 256, 0, stream>>>(Cb, Sb, data, mf, P, Q, K);
    long long totalPQ = (long long)B_ * K * C_;
    combine_kernel<<<(int)((totalPQ + 255) / 256), 256, 0, stream>>>(P, Q, cphi, sphi, denc, dens, K);
    gemm2_kernel<<<dim3((T_ + 63) / 64, B_, SPLITK), 256, 0, stream>>>(Cb, Sb, P, Q, rpart, K);
    norm_kernel<<<B_ * C_, 256, 0, stream>>>(rpart, data, mf, cnt, out);
}

// Round 2
// 172.724 us; speedup vs baseline: 2.7926x; 2.7926x over previous
//
#include <hip/hip_runtime.h>
#include <math.h>

#define B_ 8
#define C_ 64
#define T_ 1200
#define TP 1216            // T_ padded to 64
#define KP2 4864           // K padded to 64*76 (handles K=4800 or 4801)
#define SPLITK 4
#define KCH 1216           // K-range per split in gemm2 (4*1216 = 4864)

#ifndef M_PI
#define M_PI 3.14159265358979323846
#endif

typedef _Float16 h8 __attribute__((ext_vector_type(8)));
typedef float f32x4 __attribute__((ext_vector_type(4)));

union H8 { h8 h; float4 v; _Float16 e[8]; };
union F4 { float4 v; float f[4]; };

// ---------------- mask detect + convert to float ----------------
__global__ void mask_convert_kernel(const void* __restrict__ mask_raw,
                                    float* __restrict__ mf, int n) {
    __shared__ int s_bad_int, s_bad_flt;
    if (threadIdx.x == 0) { s_bad_int = 0; s_bad_flt = 0; }
    __syncthreads();
    const unsigned int* wi = (const unsigned int*)mask_raw;
    const float* wf = (const float*)mask_raw;
    int nw = n >> 2;
    int badI = 0, badF = 0;
    for (int i = threadIdx.x; i < nw; i += blockDim.x) {
        unsigned int v = wi[i];
        if (v > 1u) badI = 1;
        float f = wf[i];
        if (!(f == 0.0f || f == 1.0f)) badF = 1;
    }
    if (badI) s_bad_int = 1;
    if (badF) s_bad_flt = 1;
    __syncthreads();
    int mode = (!s_bad_int) ? 0 : ((!s_bad_flt) ? 1 : 2);
    for (int i = threadIdx.x; i < n; i += blockDim.x) {
        float v;
        if (mode == 0)      v = (float)((const int*)mask_raw)[i];
        else if (mode == 1) v = ((const float*)mask_raw)[i];
        else                v = (float)((const unsigned char*)mask_raw)[i];
        mf[i] = v;
    }
}

__global__ void cnt_kernel(const float* __restrict__ mf, float* __restrict__ cnt) {
    __shared__ float red[256];
    int b = blockIdx.x;
    float s = 0.f;
    for (int t = threadIdx.x; t < T_; t += 256) s += mf[b * T_ + t];
    red[threadIdx.x] = s; __syncthreads();
    for (int w = 128; w > 0; w >>= 1) {
        if (threadIdx.x < w) red[threadIdx.x] += red[threadIdx.x + w];
        __syncthreads();
    }
    if (threadIdx.x == 0) cnt[b] = red[0];
}

// ---------------- zero a contiguous float4 region ----------------
__global__ void zero_kernel(float4* __restrict__ p, long long n) {
    long long i = (long long)blockIdx.x * blockDim.x + threadIdx.x;
    long long stride = (long long)gridDim.x * blockDim.x;
    float4 z = make_float4(0.f, 0.f, 0.f, 0.f);
    for (; i < n; i += stride) p[i] = z;
}

// ---------------- dm_h[b][c][t] = fp16(data*m), t padded ----------------
__global__ void prep_dm_kernel(const float* __restrict__ data, const float* __restrict__ mf,
                               _Float16* __restrict__ dm_h) {
    int idx = blockIdx.x * 256 + threadIdx.x;
    if (idx >= B_ * C_ * TP) return;
    int t = idx % TP;
    int bc = idx / TP;
    int b = bc >> 6;
    float v = 0.f;
    if (t < T_) v = data[bc * T_ + t] * mf[b * T_ + t];
    dm_h[idx] = (_Float16)v;
}

// ---------------- basis tile generator + tau partial sums ----------------
// Writes Cb_h/Sb_h [k][TP] and (via LDS transpose) CbT/SbT [t][KP2] fp16.
// Accumulates S2[b,k]=sum_t m*sin(2wt), C2[b,k]=sum_t m*cos(2wt) via atomics.
__global__ __launch_bounds__(256) void basis2_kernel(
    const float* __restrict__ mf,
    _Float16* __restrict__ Cb_h, _Float16* __restrict__ Sb_h,
    _Float16* __restrict__ CbT, _Float16* __restrict__ SbT,
    float* __restrict__ S2, float* __restrict__ C2,
    double fstep, int K) {
    __shared__ _Float16 sC[64][72], sS[64][72];
    int k0 = blockIdx.x * 64, t0 = blockIdx.y * 64;
    int tid = threadIdx.x;
    int kk = tid >> 2, tq = tid & 3;
    int k = k0 + kk;
    double om = 2.0 * M_PI * (double)(k + 1) * fstep;
    float omf = (float)om;
    double w = (double)omf;
    float cf[16], sf[16];
    float s2a[B_], c2a[B_];
#pragma unroll
    for (int b = 0; b < B_; b++) { s2a[b] = 0.f; c2a[b] = 0.f; }
    bool valid = (k < K);
#pragma unroll
    for (int e = 0; e < 16; e++) {
        int t = t0 + tq * 16 + e;
        float c = 0.f, s = 0.f;
        if (valid && t < T_) {
            double ss, cc;
            sincos(w * (double)(t + 1), &ss, &cc);
            c = (float)cc; s = (float)ss;
            float sin2 = 2.f * s * c;
            float cos2 = (c - s) * (c + s);
#pragma unroll
            for (int b = 0; b < B_; b++) {
                float m = mf[b * T_ + t];
                s2a[b] = fmaf(m, sin2, s2a[b]);
                c2a[b] = fmaf(m, cos2, c2a[b]);
            }
        }
        cf[e] = c; sf[e] = s;
    }
    // reduce across the 4 threads (adjacent lanes) sharing one k
#pragma unroll
    for (int b = 0; b < B_; b++) {
        s2a[b] += __shfl_xor(s2a[b], 1); s2a[b] += __shfl_xor(s2a[b], 2);
        c2a[b] += __shfl_xor(c2a[b], 1); c2a[b] += __shfl_xor(c2a[b], 2);
    }
    if (tq == 0 && valid) {
#pragma unroll
        for (int b = 0; b < B_; b++) {
            atomicAdd(&S2[b * KP2 + k], s2a[b]);
            atomicAdd(&C2[b * KP2 + k], c2a[b]);
        }
    }
    // fp16 row writes [k][t]
    H8 p0, p1, q0, q1;
#pragma unroll
    for (int e = 0; e < 8; e++) {
        p0.e[e] = (_Float16)cf[e];     p1.e[e] = (_Float16)cf[e + 8];
        q0.e[e] = (_Float16)sf[e];     q1.e[e] = (_Float16)sf[e + 8];
    }
    size_t rowoff = (size_t)k * TP + t0 + tq * 16;
    *(float4*)&Cb_h[rowoff] = p0.v;  *(float4*)&Cb_h[rowoff + 8] = p1.v;
    *(float4*)&Sb_h[rowoff] = q0.v;  *(float4*)&Sb_h[rowoff + 8] = q1.v;
    // LDS stage for transpose
    *(float4*)&sC[kk][tq * 16] = p0.v;  *(float4*)&sC[kk][tq * 16 + 8] = p1.v;
    *(float4*)&sS[kk][tq * 16] = q0.v;  *(float4*)&sS[kk][tq * 16 + 8] = q1.v;
    __syncthreads();
    int tloc = tid >> 2, kq = tid & 3;
    H8 u0, u1, v0, v1;
#pragma unroll
    for (int e = 0; e < 8; e++) {
        u0.e[e] = sC[kq * 16 + e][tloc];
        u1.e[e] = sC[kq * 16 + 8 + e][tloc];
        v0.e[e] = sS[kq * 16 + e][tloc];
        v1.e[e] = sS[kq * 16 + 8 + e][tloc];
    }
    size_t toff = (size_t)(t0 + tloc) * KP2 + k0 + kq * 16;
    *(float4*)&CbT[toff] = u0.v;  *(float4*)&CbT[toff + 8] = u1.v;
    *(float4*)&SbT[toff] = v0.v;  *(float4*)&SbT[toff + 8] = v1.v;
}

// ---------------- phi + denominators per (b,k) ----------------
__global__ void phi_kernel(const float* __restrict__ S2, const float* __restrict__ C2,
                           const float* __restrict__ cnt,
                           float* __restrict__ cphi, float* __restrict__ sphi,
                           float* __restrict__ denc, float* __restrict__ dens) {
    int idx = blockIdx.x * 256 + threadIdx.x;
    if (idx >= B_ * KP2) return;
    int b = idx / KP2;
    float s2 = S2[idx], c2 = C2[idx];
    float phi = 0.5f * atan2f(s2, c2);
    float cp = cosf(phi), sp = sinf(phi);
    float cn = cnt[b];
    float A = 0.5f * (cn + c2), D = 0.5f * (cn - c2), E = 0.5f * s2;
    cphi[idx] = cp; sphi[idx] = sp;
    denc[idx] = cp * cp * A + 2.f * cp * sp * E + sp * sp * D;
    dens[idx] = sp * sp * A - 2.f * cp * sp * E + cp * cp * D;
}

// ---------------- GEMM1 (MFMA): P/Q[b,k,c] = sum_t basis[k,t]*dm[b,c,t] ----------------
__global__ __launch_bounds__(256) void gemm1_mfma(
    const _Float16* __restrict__ Cb_h, const _Float16* __restrict__ Sb_h,
    const _Float16* __restrict__ dm_h,
    float* __restrict__ P, float* __restrict__ Q) {
    __shared__ _Float16 sC[64][72], sS[64][72], sD[64][72];
    int b = blockIdx.y;
    int k0 = blockIdx.x * 64;
    int tid = threadIdx.x, lane = tid & 63, wv = tid >> 6;
    int row = tid >> 2, tq = tid & 3;
    f32x4 accP[4], accQ[4];
#pragma unroll
    for (int j = 0; j < 4; j++) { accP[j] = (f32x4){0.f,0.f,0.f,0.f}; accQ[j] = (f32x4){0.f,0.f,0.f,0.f}; }
    int frow = (wv << 4) + (lane & 15);
    int fk = (lane >> 4) << 3;
    size_t crow = (size_t)(k0 + row) * TP;
    size_t drow = ((size_t)b * 64 + row) * TP;
    for (int tc = 0; tc < TP; tc += 64) {
        float4 c0 = *(const float4*)&Cb_h[crow + tc + tq * 16];
        float4 c1 = *(const float4*)&Cb_h[crow + tc + tq * 16 + 8];
        float4 s0 = *(const float4*)&Sb_h[crow + tc + tq * 16];
        float4 s1 = *(const float4*)&Sb_h[crow + tc + tq * 16 + 8];
        float4 d0 = *(const float4*)&dm_h[drow + tc + tq * 16];
        float4 d1 = *(const float4*)&dm_h[drow + tc + tq * 16 + 8];
        __syncthreads();
        *(float4*)&sC[row][tq * 16] = c0;  *(float4*)&sC[row][tq * 16 + 8] = c1;
        *(float4*)&sS[row][tq * 16] = s0;  *(float4*)&sS[row][tq * 16 + 8] = s1;
        *(float4*)&sD[row][tq * 16] = d0;  *(float4*)&sD[row][tq * 16 + 8] = d1;
        __syncthreads();
#pragma unroll
        for (int ks = 0; ks < 64; ks += 32) {
            h8 ac = *(h8*)&sC[frow][ks + fk];
            h8 as = *(h8*)&sS[frow][ks + fk];
#pragma unroll
            for (int j = 0; j < 4; j++) {
                h8 bd = *(h8*)&sD[(j << 4) + (lane & 15)][ks + fk];
                accP[j] = __builtin_amdgcn_mfma_f32_16x16x32_f16(ac, bd, accP[j], 0, 0, 0);
                accQ[j] = __builtin_amdgcn_mfma_f32_16x16x32_f16(as, bd, accQ[j], 0, 0, 0);
            }
        }
    }
    int kout = k0 + (wv << 4) + ((lane >> 4) << 2);
    int cbase = lane & 15;
#pragma unroll
    for (int j = 0; j < 4; j++) {
#pragma unroll
        for (int r = 0; r < 4; r++) {
            size_t oidx = ((size_t)b * KP2 + kout + r) * 64 + (j << 4) + cbase;
            P[oidx] = accP[j][r];
            Q[oidx] = accQ[j][r];
        }
    }
}

// ---------------- combine: (P,Q)->(U,V), emit fp16 transposed [b][c][k] ----------------
__global__ __launch_bounds__(256) void combine2_kernel(
    const float* __restrict__ P, const float* __restrict__ Q,
    const float* __restrict__ cphi, const float* __restrict__ sphi,
    const float* __restrict__ denc, const float* __restrict__ dens,
    _Float16* __restrict__ Uh, _Float16* __restrict__ Vh) {
    __shared__ _Float16 sU[64][72], sV[64][72];
    int b = blockIdx.y, k0 = blockIdx.x * 64;
    int tid = threadIdx.x;
    int kk = tid >> 2, cq = tid & 3;
    int gidx = b * KP2 + k0 + kk;
    float cp = cphi[gidx], sp = sphi[gidx];
    float rdc = 1.f / denc[gidx], rds = 1.f / dens[gidx];
    _Float16 uh[16], vh[16];
#pragma unroll
    for (int e4 = 0; e4 < 4; e4++) {
        F4 pv, qv;
        pv.v = *(const float4*)&P[(size_t)gidx * 64 + cq * 16 + e4 * 4];
        qv.v = *(const float4*)&Q[(size_t)gidx * 64 + cq * 16 + e4 * 4];
#pragma unroll
        for (int e = 0; e < 4; e++) {
            float p = pv.f[e], q = qv.f[e];
            float cc = (cp * p + sp * q) * rdc;
            float sc = (cp * q - sp * p) * rds;
            uh[e4 * 4 + e] = (_Float16)(cp * cc - sp * sc);
            vh[e4 * 4 + e] = (_Float16)(sp * cc + cp * sc);
        }
    }
    H8 a0, a1, b0v, b1v;
#pragma unroll
    for (int e = 0; e < 8; e++) { a0.e[e] = uh[e]; a1.e[e] = uh[e + 8]; b0v.e[e] = vh[e]; b1v.e[e] = vh[e + 8]; }
    *(float4*)&sU[kk][cq * 16] = a0.v;  *(float4*)&sU[kk][cq * 16 + 8] = a1.v;
    *(float4*)&sV[kk][cq * 16] = b0v.v; *(float4*)&sV[kk][cq * 16 + 8] = b1v.v;
    __syncthreads();
    int c = tid >> 2, kq = tid & 3;
    H8 o0, o1, o2, o3;
#pragma unroll
    for (int e = 0; e < 8; e++) {
        o0.e[e] = sU[kq * 16 + e][c];
        o1.e[e] = sU[kq * 16 + 8 + e][c];
        o2.e[e] = sV[kq * 16 + e][c];
        o3.e[e] = sV[kq * 16 + 8 + e][c];
    }
    size_t ooff = ((size_t)b * 64 + c) * KP2 + k0 + kq * 16;
    *(float4*)&Uh[ooff] = o0.v;  *(float4*)&Uh[ooff + 8] = o1.v;
    *(float4*)&Vh[ooff] = o2.v;  *(float4*)&Vh[ooff + 8] = o3.v;
}

// ---------------- GEMM2 (MFMA): rpart[sk,b,c,t] = sum_k U*C + V*S ----------------
__global__ __launch_bounds__(256) void gemm2_mfma(
    const _Float16* __restrict__ Uh, const _Float16* __restrict__ Vh,
    const _Float16* __restrict__ CbT, const _Float16* __restrict__ SbT,
    float* __restrict__ rpart) {
    __shared__ _Float16 sU[64][72], sV[64][72], sCT[64][72], sST[64][72];
    int t0 = blockIdx.x * 64, b = blockIdx.y, sk = blockIdx.z;
    int kbase = sk * KCH;
    int tid = threadIdx.x, lane = tid & 63, wv = tid >> 6;
    int row = tid >> 2, tq = tid & 3;
    f32x4 acc[4];
#pragma unroll
    for (int j = 0; j < 4; j++) acc[j] = (f32x4){0.f,0.f,0.f,0.f};
    int frow = (wv << 4) + (lane & 15);
    int fk = (lane >> 4) << 3;
    size_t urow = ((size_t)b * 64 + row) * KP2 + kbase;
    size_t crow = (size_t)(t0 + row) * KP2 + kbase;
    for (int kc = 0; kc < KCH; kc += 64) {
        float4 u0 = *(const float4*)&Uh[urow + kc + tq * 16];
        float4 u1 = *(const float4*)&Uh[urow + kc + tq * 16 + 8];
        float4 v0 = *(const float4*)&Vh[urow + kc + tq * 16];
        float4 v1 = *(const float4*)&Vh[urow + kc + tq * 16 + 8];
        float4 c0 = *(const float4*)&CbT[crow + kc + tq * 16];
        float4 c1 = *(const float4*)&CbT[crow + kc + tq * 16 + 8];
        float4 s0 = *(const float4*)&SbT[crow + kc + tq * 16];
        float4 s1 = *(const float4*)&SbT[crow + kc + tq * 16 + 8];
        __syncthreads();
        *(float4*)&sU[row][tq * 16] = u0;   *(float4*)&sU[row][tq * 16 + 8] = u1;
        *(float4*)&sV[row][tq * 16] = v0;   *(float4*)&sV[row][tq * 16 + 8] = v1;
        *(float4*)&sCT[row][tq * 16] = c0;  *(float4*)&sCT[row][tq * 16 + 8] = c1;
        *(float4*)&sST[row][tq * 16] = s0;  *(float4*)&sST[row][tq * 16 + 8] = s1;
        __syncthreads();
#pragma unroll
        for (int ks = 0; ks < 64; ks += 32) {
            h8 au = *(h8*)&sU[frow][ks + fk];
            h8 av = *(h8*)&sV[frow][ks + fk];
#pragma unroll
            for (int j = 0; j < 4; j++) {
                h8 bc = *(h8*)&sCT[(j << 4) + (lane & 15)][ks + fk];
                h8 bs = *(h8*)&sST[(j << 4) + (lane & 15)][ks + fk];
                acc[j] = __builtin_amdgcn_mfma_f32_16x16x32_f16(au, bc, acc[j], 0, 0, 0);
                acc[j] = __builtin_amdgcn_mfma_f32_16x16x32_f16(av, bs, acc[j], 0, 0, 0);
            }
        }
    }
    int cout = (wv << 4) + ((lane >> 4) << 2);
    int tb = lane & 15;
#pragma unroll
    for (int j = 0; j < 4; j++) {
#pragma unroll
        for (int r = 0; r < 4; r++) {
            int t = t0 + (j << 4) + tb;
            if (t < T_)
                rpart[(((size_t)sk * B_ + b) * 64 + cout + r) * T_ + t] = acc[j][r];
        }
    }
}

// ---------------- normalize + select ----------------
__global__ void norm_kernel(const float* __restrict__ rpart, const float* __restrict__ data,
                            const float* __restrict__ mf, const float* __restrict__ cnt,
                            float* __restrict__ out) {
    __shared__ float red[256];
    __shared__ float s_meanr, s_mu, s_scale;
    int bc = blockIdx.x;
    int b = bc >> 6;
    const size_t base = (size_t)bc * T_;
    const size_t stride = (size_t)B_ * C_ * T_;
    float sr = 0.f, sd = 0.f;
    for (int t = threadIdx.x; t < T_; t += 256) {
        float r = rpart[base + t] + rpart[stride + base + t]
                + rpart[2 * stride + base + t] + rpart[3 * stride + base + t];
        sr += r;
        sd += data[base + t] * mf[b * T_ + t];
    }
    red[threadIdx.x] = sr; __syncthreads();
    for (int w = 128; w > 0; w >>= 1) { if (threadIdx.x < w) red[threadIdx.x] += red[threadIdx.x + w]; __syncthreads(); }
    if (threadIdx.x == 0) s_meanr = red[0] / (float)T_;
    __syncthreads();
    red[threadIdx.x] = sd; __syncthreads();
    for (int w = 128; w > 0; w >>= 1) { if (threadIdx.x < w) red[threadIdx.x] += red[threadIdx.x + w]; __syncthreads(); }
    if (threadIdx.x == 0) s_mu = red[0] / cnt[b];
    __syncthreads();
    float meanr = s_meanr, mu = s_mu;
    float vr = 0.f, vd = 0.f;
    for (int t = threadIdx.x; t < T_; t += 256) {
        float r = rpart[base + t] + rpart[stride + base + t]
                + rpart[2 * stride + base + t] + rpart[3 * stride + base + t];
        float dr = r - meanr; vr += dr * dr;
        float x = data[base + t];
        float m = mf[b * T_ + t];
        float dx = x - mu; vd += dx * dx * m;
    }
    red[threadIdx.x] = vr; __syncthreads();
    for (int w = 128; w > 0; w >>= 1) { if (threadIdx.x < w) red[threadIdx.x] += red[threadIdx.x + w]; __syncthreads(); }
    float varr = red[0];
    __syncthreads();
    red[threadIdx.x] = vd; __syncthreads();
    for (int w = 128; w > 0; w >>= 1) { if (threadIdx.x < w) red[threadIdx.x] += red[threadIdx.x + w]; __syncthreads(); }
    if (threadIdx.x == 0) {
        float sdr = sqrtf(varr / (float)(T_ - 1));
        float sdo = sqrtf(red[0] / (cnt[b] - 1.0f));
        s_scale = sdo / sdr;
    }
    __syncthreads();
    float scale = s_scale;
    for (int t = threadIdx.x; t < T_; t += 256) {
        float r = rpart[base + t] + rpart[stride + base + t]
                + rpart[2 * stride + base + t] + rpart[3 * stride + base + t];
        float m = mf[b * T_ + t];
        out[base + t] = (m > 0.5f) ? data[base + t] : r * scale;
    }
}

extern "C" void kernel_launch(void* const* d_in, const int* in_sizes, int n_in,
                              void* d_out, int out_size, void* d_ws, size_t ws_size,
                              hipStream_t stream) {
    const float* data = (const float*)d_in[0];
    const void* mask = d_in[1];
    float* out = (float*)d_out;

    // Replicate numpy arange length computation exactly (double precision).
    const double timespan = 1.0 * (T_ + 1) - 1.0;               // 1200
    const double fstep = 1.0 / (timespan * 8.0);                // OSFREQ = 8
    const double stop = (1.0 * (double)T_) / (2.0 * timespan) + fstep;
    const int K = (int)ceil((stop - fstep) / fstep);            // 4800 (or 4801)
    const int KT = (K + 63) / 64;                                // k tiles

    char* w = (char*)d_ws;
    auto alloc = [&](size_t nbytes) {
        char* p = w;
        w += ((nbytes + 255) / 256) * 256;
        return p;
    };
    float*     mf   = (float*)    alloc((size_t)B_ * T_ * 4);
    float*     cnt  = (float*)    alloc(B_ * 4);
    // ---- zero region start ----
    char* zstart = w;
    float*     S2   = (float*)    alloc((size_t)B_ * KP2 * 4);
    float*     C2   = (float*)    alloc((size_t)B_ * KP2 * 4);
    _Float16*  CbT  = (_Float16*) alloc((size_t)TP * KP2 * 2);
    _Float16*  SbT  = (_Float16*) alloc((size_t)TP * KP2 * 2);
    _Float16*  Uh   = (_Float16*) alloc((size_t)B_ * 64 * KP2 * 2);
    _Float16*  Vh   = (_Float16*) alloc((size_t)B_ * 64 * KP2 * 2);
    char* zend = w;
    // ---- zero region end ----
    float*     cphi = (float*)    alloc((size_t)B_ * KP2 * 4);
    float*     sphi = (float*)    alloc((size_t)B_ * KP2 * 4);
    float*     denc = (float*)    alloc((size_t)B_ * KP2 * 4);
    float*     dens = (float*)    alloc((size_t)B_ * KP2 * 4);
    _Float16*  Cb_h = (_Float16*) alloc((size_t)KP2 * TP * 2);
    _Float16*  Sb_h = (_Float16*) alloc((size_t)KP2 * TP * 2);
    _Float16*  dm_h = (_Float16*) alloc((size_t)B_ * C_ * TP * 2);
    float*     P    = (float*)    alloc((size_t)B_ * KP2 * 64 * 4);
    float*     Q    = (float*)    alloc((size_t)B_ * KP2 * 64 * 4);
    float*     rpart= (float*)    alloc((size_t)SPLITK * B_ * C_ * T_ * 4);
    (void)ws_size; (void)in_sizes; (void)n_in; (void)out_size;

    mask_convert_kernel<<<1, 256, 0, stream>>>(mask, mf, B_ * T_);
    cnt_kernel<<<B_, 256, 0, stream>>>(mf, cnt);
    long long zn = (long long)(zend - zstart) / 16;
    zero_kernel<<<2048, 256, 0, stream>>>((float4*)zstart, zn);
    prep_dm_kernel<<<(B_ * C_ * TP + 255) / 256, 256, 0, stream>>>(data, mf, dm_h);
    basis2_kernel<<<dim3(KT, TP / 64), 256, 0, stream>>>(mf, Cb_h, Sb_h, CbT, SbT, S2, C2, fstep, K);
    phi_kernel<<<(B_ * KP2 + 255) / 256, 256, 0, stream>>>(S2, C2, cnt, cphi, sphi, denc, dens);
    gemm1_mfma<<<dim3(KT, B_), 256, 0, stream>>>(Cb_h, Sb_h, dm_h, P, Q);
    combine2_kernel<<<dim3(KT, B_), 256, 0, stream>>>(P, Q, cphi, sphi, denc, dens, Uh, Vh);
    gemm2_mfma<<<dim3(TP / 64, B_, SPLITK), 256, 0, stream>>>(Uh, Vh, CbT, SbT, rpart);
    norm_kernel<<<B_ * C_, 256, 0, stream>>>(rpart, data, mf, cnt, out);
}

// Round 3
// 137.750 us; speedup vs baseline: 3.5017x; 1.2539x over previous
//
#include <hip/hip_runtime.h>
#include <math.h>

#define B_ 8
#define C_ 64
#define M_ 512            // B_*C_
#define T_ 1200
#define TP 1216           // T_ padded to 64
#define KP 4864           // K padded to 64 (K = 4800)
#define K2P 9728          // 2*KP, interleaved cos/sin rows
#define SPLITK 4
#define KCH (K2P / SPLITK)   // 2432

#ifndef M_PI
#define M_PI 3.14159265358979323846
#endif

typedef _Float16 h8 __attribute__((ext_vector_type(8)));
typedef float f32x4 __attribute__((ext_vector_type(4)));
union H8 { h8 h; float4 v; _Float16 e[8]; };
union HP { _Float16 hh[2]; unsigned u; };

// ---------------- mask detect + convert to float ----------------
__global__ void mask_convert_kernel(const void* __restrict__ mask_raw,
                                    float* __restrict__ mf, int n) {
    __shared__ int s_bad_int, s_bad_flt;
    if (threadIdx.x == 0) { s_bad_int = 0; s_bad_flt = 0; }
    __syncthreads();
    const unsigned int* wi = (const unsigned int*)mask_raw;
    const float* wf = (const float*)mask_raw;
    int nw = n >> 2;
    int badI = 0, badF = 0;
    for (int i = threadIdx.x; i < nw; i += blockDim.x) {
        unsigned int v = wi[i];
        if (v > 1u) badI = 1;
        float f = wf[i];
        if (!(f == 0.0f || f == 1.0f)) badF = 1;
    }
    if (badI) s_bad_int = 1;
    if (badF) s_bad_flt = 1;
    __syncthreads();
    int mode = (!s_bad_int) ? 0 : ((!s_bad_flt) ? 1 : 2);
    for (int i = threadIdx.x; i < n; i += blockDim.x) {
        float v;
        if (mode == 0)      v = (float)((const int*)mask_raw)[i];
        else if (mode == 1) v = ((const float*)mask_raw)[i];
        else                v = (float)((const unsigned char*)mask_raw)[i];
        mf[i] = v;
    }
}

__global__ void cnt_kernel(const float* __restrict__ mf, float* __restrict__ cnt) {
    __shared__ float red[256];
    int b = blockIdx.x;
    float s = 0.f;
    for (int t = threadIdx.x; t < T_; t += 256) s += mf[b * T_ + t];
    red[threadIdx.x] = s; __syncthreads();
    for (int w = 128; w > 0; w >>= 1) {
        if (threadIdx.x < w) red[threadIdx.x] += red[threadIdx.x + w];
        __syncthreads();
    }
    if (threadIdx.x == 0) cnt[b] = red[0];
}

__global__ void zero_kernel(float4* __restrict__ p, long long n) {
    long long i = (long long)blockIdx.x * blockDim.x + threadIdx.x;
    long long stride = (long long)gridDim.x * blockDim.x;
    float4 z = make_float4(0.f, 0.f, 0.f, 0.f);
    for (; i < n; i += stride) p[i] = z;
}

// ---------------- dm_h[bc][TP] = fp16(data*m) ----------------
__global__ void prep_dm_kernel(const float* __restrict__ data, const float* __restrict__ mf,
                               _Float16* __restrict__ dm_h) {
    int idx = blockIdx.x * 256 + threadIdx.x;
    if (idx >= M_ * TP) return;
    int t = idx % TP;
    int bc = idx / TP;
    int b = bc >> 6;
    float v = 0.f;
    if (t < T_) v = data[bc * T_ + t] * mf[b * T_ + t];
    dm_h[idx] = (_Float16)v;
}

// ---------------- basis: Z[2k(+1)][t] (cos/sin interleaved), ZT[t][k2], tau sums ----------------
__global__ __launch_bounds__(256) void basis3_kernel(
    const float* __restrict__ mf,
    _Float16* __restrict__ Z, _Float16* __restrict__ ZT,
    float* __restrict__ S2, float* __restrict__ C2,
    double fstep, int K) {
    __shared__ _Float16 sZ[64 * 136];
    int k0 = blockIdx.x * 64, t0 = blockIdx.y * 64;
    int tid = threadIdx.x;
    int kk = tid >> 2, tq = tid & 3;
    int k = k0 + kk;
    double om = 2.0 * M_PI * (fstep + (double)k * fstep);
    double w = (double)((float)om);   // reference rounds omega to f32
    bool valid = (k < K);
    float cf[16], sf[16];
    float s2a[B_], c2a[B_];
#pragma unroll
    for (int b = 0; b < B_; b++) { s2a[b] = 0.f; c2a[b] = 0.f; }
    // one double sincos + rotation recurrence for the 16 t's
    double cB, sB, cw, sw;
    sincos(w * (double)(t0 + tq * 16 + 1), &sB, &cB);
    sincos(w, &sw, &cw);
    double cd = cB, sd = sB;
#pragma unroll
    for (int e = 0; e < 16; e++) {
        int t = t0 + tq * 16 + e;
        float c = 0.f, s = 0.f;
        if (valid && t < T_) {
            c = (float)cd; s = (float)sd;
            float sin2 = 2.f * s * c;
            float cos2 = (c - s) * (c + s);
#pragma unroll
            for (int b = 0; b < B_; b++) {
                float m = mf[b * T_ + t];
                s2a[b] = fmaf(m, sin2, s2a[b]);
                c2a[b] = fmaf(m, cos2, c2a[b]);
            }
        }
        cf[e] = c; sf[e] = s;
        double cn = cd * cw - sd * sw;
        sd = sd * cw + cd * sw;
        cd = cn;
    }
#pragma unroll
    for (int b = 0; b < B_; b++) {
        s2a[b] += __shfl_xor(s2a[b], 1); s2a[b] += __shfl_xor(s2a[b], 2);
        c2a[b] += __shfl_xor(c2a[b], 1); c2a[b] += __shfl_xor(c2a[b], 2);
    }
    if (tq == 0 && valid) {
#pragma unroll
        for (int b = 0; b < B_; b++) {
            atomicAdd(&S2[b * KP + k], s2a[b]);
            atomicAdd(&C2[b * KP + k], c2a[b]);
        }
    }
    // Z rows 2k (cos), 2k+1 (sin)
    H8 pc0, pc1, ps0, ps1;
#pragma unroll
    for (int e = 0; e < 8; e++) {
        pc0.e[e] = (_Float16)cf[e];  pc1.e[e] = (_Float16)cf[e + 8];
        ps0.e[e] = (_Float16)sf[e];  ps1.e[e] = (_Float16)sf[e + 8];
    }
    size_t zoff = (size_t)(2 * k) * TP + t0 + tq * 16;
    *(float4*)&Z[zoff] = pc0.v;       *(float4*)&Z[zoff + 8] = pc1.v;
    *(float4*)&Z[zoff + TP] = ps0.v;  *(float4*)&Z[zoff + TP + 8] = ps1.v;
    // LDS transpose to ZT[t][k2]
#pragma unroll
    for (int e = 0; e < 16; e++) {
        HP pk; pk.hh[0] = (_Float16)cf[e]; pk.hh[1] = (_Float16)sf[e];
        *(unsigned*)&sZ[(tq * 16 + e) * 136 + 2 * kk] = pk.u;
    }
    __syncthreads();
    int tl = tid >> 2, kq = tid & 3;
    float4 o0 = *(float4*)&sZ[tl * 136 + kq * 32];
    float4 o1 = *(float4*)&sZ[tl * 136 + kq * 32 + 8];
    float4 o2 = *(float4*)&sZ[tl * 136 + kq * 32 + 16];
    float4 o3 = *(float4*)&sZ[tl * 136 + kq * 32 + 24];
    size_t toff = (size_t)(t0 + tl) * K2P + 2 * k0 + kq * 32;
    *(float4*)&ZT[toff] = o0;       *(float4*)&ZT[toff + 8] = o1;
    *(float4*)&ZT[toff + 16] = o2;  *(float4*)&ZT[toff + 24] = o3;
}

// ---------------- phi + reciprocal denominators ----------------
__global__ void phi_kernel(const float* __restrict__ S2, const float* __restrict__ C2,
                           const float* __restrict__ cnt,
                           float* __restrict__ cphi, float* __restrict__ sphi,
                           float* __restrict__ rdc, float* __restrict__ rds) {
    int idx = blockIdx.x * 256 + threadIdx.x;
    if (idx >= B_ * KP) return;
    int b = idx / KP;
    float s2 = S2[idx], c2 = C2[idx];
    float phi = 0.5f * atan2f(s2, c2);
    float cp = cosf(phi), sp = sinf(phi);
    float cn = cnt[b];
    float A = 0.5f * (cn + c2), D = 0.5f * (cn - c2), E = 0.5f * s2;
    cphi[idx] = cp; sphi[idx] = sp;
    rdc[idx] = 1.f / (cp * cp * A + 2.f * cp * sp * E + sp * sp * D);
    rds[idx] = 1.f / (sp * sp * A - 2.f * cp * sp * E + cp * cp * D);
}

// swizzled LDS offset (halves): row stride 64 halves, 16B chunk index XOR'd with row&7
__device__ __forceinline__ int swz(int row, int c16) {
    return row * 64 + ((c16 ^ (row & 7)) << 3);
}

// ---------------- GEMM1: W[bc][k2] = sum_t dm[bc][t] * Z[k2][t], fused LS-combine ----------------
__global__ __launch_bounds__(256) void gemm1x(
    const _Float16* __restrict__ dm, const _Float16* __restrict__ Z,
    const float* __restrict__ cphi, const float* __restrict__ sphi,
    const float* __restrict__ rdc, const float* __restrict__ rds,
    _Float16* __restrict__ W) {
    __shared__ _Float16 sA[128 * 64], sB[64 * 64];
    int bx = blockIdx.x;                       // 608 = 8 * (4 * 19)
    int xcd = bx & 7, rem = bx >> 3;
    int mt = rem & 3, g = rem >> 2;            // g 0..18
    int nt = xcd + 8 * g;                      // 0..151; same nt -> same XCD
    int m0 = mt * 128, n0 = nt * 64;
    int tid = threadIdx.x, lane = tid & 63, wv = tid >> 6;
    f32x4 acc[2][4];
#pragma unroll
    for (int i = 0; i < 2; i++)
#pragma unroll
        for (int j = 0; j < 4; j++) acc[i][j] = (f32x4){0.f, 0.f, 0.f, 0.f};
    int ar = tid >> 1, ah = tid & 1;
    int br = tid >> 2, bq = tid & 3;
    const _Float16* gA = dm + (size_t)(m0 + ar) * TP;
    const _Float16* gB = Z + (size_t)(n0 + br) * TP;
    for (int rc = 0; rc < TP; rc += 64) {
        float4 va0 = *(const float4*)&gA[rc + (ah * 4 + 0) * 8];
        float4 va1 = *(const float4*)&gA[rc + (ah * 4 + 1) * 8];
        float4 va2 = *(const float4*)&gA[rc + (ah * 4 + 2) * 8];
        float4 va3 = *(const float4*)&gA[rc + (ah * 4 + 3) * 8];
        float4 vb0 = *(const float4*)&gB[rc + (bq * 2 + 0) * 8];
        float4 vb1 = *(const float4*)&gB[rc + (bq * 2 + 1) * 8];
        __syncthreads();
        *(float4*)&sA[swz(ar, ah * 4 + 0)] = va0;
        *(float4*)&sA[swz(ar, ah * 4 + 1)] = va1;
        *(float4*)&sA[swz(ar, ah * 4 + 2)] = va2;
        *(float4*)&sA[swz(ar, ah * 4 + 3)] = va3;
        *(float4*)&sB[swz(br, bq * 2 + 0)] = vb0;
        *(float4*)&sB[swz(br, bq * 2 + 1)] = vb1;
        __syncthreads();
#pragma unroll
        for (int ks = 0; ks < 2; ks++) {
            int c16 = ks * 4 + (lane >> 4);
            int r0 = 32 * wv + (lane & 15);
            int r1 = r0 + 16;
            h8 a0 = *(h8*)&sA[swz(r0, c16)];
            h8 a1 = *(h8*)&sA[swz(r1, c16)];
#pragma unroll
            for (int j = 0; j < 4; j++) {
                int rb = 16 * j + (lane & 15);
                h8 bfr = *(h8*)&sB[swz(rb, c16)];
                acc[0][j] = __builtin_amdgcn_mfma_f32_16x16x32_f16(a0, bfr, acc[0][j], 0, 0, 0);
                acc[1][j] = __builtin_amdgcn_mfma_f32_16x16x32_f16(a1, bfr, acc[1][j], 0, 0, 0);
            }
        }
    }
    // epilogue: Lomb-Scargle combine in-register, write fp16 W[bc][k2]
    int colb = lane & 15;
    int par = colb & 1;                        // 0: cos row (P->U), 1: sin row (Q->V)
#pragma unroll
    for (int i = 0; i < 2; i++) {
        int mbase = m0 + 32 * wv + 16 * i + ((lane >> 4) << 2);
        int b = mbase >> 6;
#pragma unroll
        for (int j = 0; j < 4; j++) {
            int k2 = n0 + 16 * j + colb;
            int kidx = b * KP + (k2 >> 1);
            float cp = cphi[kidx], sp = sphi[kidx];
            float rc_ = rdc[kidx], rs_ = rds[kidx];
            f32x4 own = acc[i][j];
            f32x4 oth;
#pragma unroll
            for (int r = 0; r < 4; r++) oth[r] = __shfl_xor(own[r], 1);
#pragma unroll
            for (int r = 0; r < 4; r++) {
                float p = par ? oth[r] : own[r];
                float q = par ? own[r] : oth[r];
                float cc = (cp * p + sp * q) * rc_;
                float sc = (cp * q - sp * p) * rs_;
                float val = par ? (sp * cc + cp * sc) : (cp * cc - sp * sc);
                W[(size_t)(mbase + r) * K2P + k2] = (_Float16)val;
            }
        }
    }
}

// ---------------- GEMM2: rpart[sk][bc][t] = sum_{k2 chunk} W[bc][k2] * ZT[t][k2] ----------------
__global__ __launch_bounds__(256) void gemm2x(
    const _Float16* __restrict__ W, const _Float16* __restrict__ ZT,
    float* __restrict__ rpart) {
    __shared__ _Float16 sA[128 * 64], sB[64 * 64];
    int bx = blockIdx.x;                       // 304 = 8 * (19 * 2)
    int xcd = bx & 7, rem = bx >> 3;
    int nt = rem % 19, q = rem / 19;
    int msk = xcd + 8 * q;                     // 0..15; same (mt,sk) -> same XCD
    int mt = msk & 3, sk = msk >> 2;
    int m0 = mt * 128, t0 = nt * 64, kbase = sk * KCH;
    int tid = threadIdx.x, lane = tid & 63, wv = tid >> 6;
    f32x4 acc[2][4];
#pragma unroll
    for (int i = 0; i < 2; i++)
#pragma unroll
        for (int j = 0; j < 4; j++) acc[i][j] = (f32x4){0.f, 0.f, 0.f, 0.f};
    int ar = tid >> 1, ah = tid & 1;
    int br = tid >> 2, bq = tid & 3;
    const _Float16* gA = W + (size_t)(m0 + ar) * K2P + kbase;
    const _Float16* gB = ZT + (size_t)(t0 + br) * K2P + kbase;
    for (int rc = 0; rc < KCH; rc += 64) {
        float4 va0 = *(const float4*)&gA[rc + (ah * 4 + 0) * 8];
        float4 va1 = *(const float4*)&gA[rc + (ah * 4 + 1) * 8];
        float4 va2 = *(const float4*)&gA[rc + (ah * 4 + 2) * 8];
        float4 va3 = *(const float4*)&gA[rc + (ah * 4 + 3) * 8];
        float4 vb0 = *(const float4*)&gB[rc + (bq * 2 + 0) * 8];
        float4 vb1 = *(const float4*)&gB[rc + (bq * 2 + 1) * 8];
        __syncthreads();
        *(float4*)&sA[swz(ar, ah * 4 + 0)] = va0;
        *(float4*)&sA[swz(ar, ah * 4 + 1)] = va1;
        *(float4*)&sA[swz(ar, ah * 4 + 2)] = va2;
        *(float4*)&sA[swz(ar, ah * 4 + 3)] = va3;
        *(float4*)&sB[swz(br, bq * 2 + 0)] = vb0;
        *(float4*)&sB[swz(br, bq * 2 + 1)] = vb1;
        __syncthreads();
#pragma unroll
        for (int ks = 0; ks < 2; ks++) {
            int c16 = ks * 4 + (lane >> 4);
            int r0 = 32 * wv + (lane & 15);
            int r1 = r0 + 16;
            h8 a0 = *(h8*)&sA[swz(r0, c16)];
            h8 a1 = *(h8*)&sA[swz(r1, c16)];
#pragma unroll
            for (int j = 0; j < 4; j++) {
                int rb = 16 * j + (lane & 15);
                h8 bfr = *(h8*)&sB[swz(rb, c16)];
                acc[0][j] = __builtin_amdgcn_mfma_f32_16x16x32_f16(a0, bfr, acc[0][j], 0, 0, 0);
                acc[1][j] = __builtin_amdgcn_mfma_f32_16x16x32_f16(a1, bfr, acc[1][j], 0, 0, 0);
            }
        }
    }
#pragma unroll
    for (int i = 0; i < 2; i++) {
        int mbase = m0 + 32 * wv + 16 * i + ((lane >> 4) << 2);
#pragma unroll
        for (int j = 0; j < 4; j++) {
            int t = t0 + 16 * j + (lane & 15);
#pragma unroll
            for (int r = 0; r < 4; r++)
                rpart[((size_t)sk * M_ + mbase + r) * TP + t] = acc[i][j][r];
        }
    }
}

// ---------------- normalize + select (2-pass, sum/sumsq) ----------------
__global__ void norm2_kernel(const float* __restrict__ rpart, const float* __restrict__ data,
                             const float* __restrict__ mf, const float* __restrict__ cnt,
                             float* __restrict__ out) {
    __shared__ float4 red[256];
    __shared__ float s_scale;
    int bc = blockIdx.x, b = bc >> 6;
    const size_t rbase = (size_t)bc * TP;
    const size_t dbase = (size_t)bc * T_;
    const size_t rstr = (size_t)M_ * TP;
    float sr = 0.f, srr = 0.f, sd = 0.f, sdd = 0.f;
    for (int t = threadIdx.x; t < T_; t += 256) {
        float r = rpart[rbase + t] + rpart[rstr + rbase + t]
                + rpart[2 * rstr + rbase + t] + rpart[3 * rstr + rbase + t];
        float x = data[dbase + t], m = mf[b * T_ + t];
        sr += r; srr += r * r; sd += x * m; sdd += x * x * m;
    }
    red[threadIdx.x] = make_float4(sr, srr, sd, sdd);
    __syncthreads();
    for (int w = 128; w > 0; w >>= 1) {
        if (threadIdx.x < w) {
            float4 a = red[threadIdx.x], c = red[threadIdx.x + w];
            red[threadIdx.x] = make_float4(a.x + c.x, a.y + c.y, a.z + c.z, a.w + c.w);
        }
        __syncthreads();
    }
    if (threadIdx.x == 0) {
        float4 v = red[0];
        float cn = cnt[b];
        float varr = (v.y - v.x * v.x / (float)T_) / (float)(T_ - 1);
        float vard = (v.w - v.z * v.z / cn) / (cn - 1.f);
        s_scale = sqrtf(vard / varr);
    }
    __syncthreads();
    float scale = s_scale;
    for (int t = threadIdx.x; t < T_; t += 256) {
        float r = rpart[rbase + t] + rpart[rstr + rbase + t]
                + rpart[2 * rstr + rbase + t] + rpart[3 * rstr + rbase + t];
        float m = mf[b * T_ + t];
        out[dbase + t] = (m > 0.5f) ? data[dbase + t] : r * scale;
    }
}

extern "C" void kernel_launch(void* const* d_in, const int* in_sizes, int n_in,
                              void* d_out, int out_size, void* d_ws, size_t ws_size,
                              hipStream_t stream) {
    const float* data = (const float*)d_in[0];
    const void* mask = d_in[1];
    float* out = (float*)d_out;

    const double timespan = 1.0 * (T_ + 1) - 1.0;               // 1200
    const double fstep = 1.0 / (timespan * 8.0);                // OSFREQ = 8
    const double stop = (1.0 * (double)T_) / (2.0 * timespan) + fstep;
    const int K = (int)ceil((stop - fstep) / fstep);            // 4800 (or 4801)

    char* w = (char*)d_ws;
    auto alloc = [&](size_t nbytes) {
        char* p = w;
        w += ((nbytes + 255) / 256) * 256;
        return p;
    };
    float*     mf    = (float*)    alloc((size_t)B_ * T_ * 4);
    float*     cnt   = (float*)    alloc(B_ * 4);
    char* zstart = w;
    float*     S2    = (float*)    alloc((size_t)B_ * KP * 4);
    float*     C2    = (float*)    alloc((size_t)B_ * KP * 4);
    char* zend = w;
    float*     cphi  = (float*)    alloc((size_t)B_ * KP * 4);
    float*     sphi  = (float*)    alloc((size_t)B_ * KP * 4);
    float*     rdc   = (float*)    alloc((size_t)B_ * KP * 4);
    float*     rds   = (float*)    alloc((size_t)B_ * KP * 4);
    _Float16*  dm_h  = (_Float16*) alloc((size_t)M_ * TP * 2);
    _Float16*  Z     = (_Float16*) alloc((size_t)K2P * TP * 2);
    _Float16*  ZT    = (_Float16*) alloc((size_t)TP * K2P * 2);
    _Float16*  W     = (_Float16*) alloc((size_t)M_ * K2P * 2);
    float*     rpart = (float*)    alloc((size_t)SPLITK * M_ * TP * 4);
    (void)ws_size; (void)in_sizes; (void)n_in; (void)out_size;

    mask_convert_kernel<<<1, 256, 0, stream>>>(mask, mf, B_ * T_);
    cnt_kernel<<<B_, 256, 0, stream>>>(mf, cnt);
    long long zn = (long long)(zend - zstart) / 16;
    zero_kernel<<<96, 256, 0, stream>>>((float4*)zstart, zn);
    prep_dm_kernel<<<(M_ * TP + 255) / 256, 256, 0, stream>>>(data, mf, dm_h);
    basis3_kernel<<<dim3(KP / 64, TP / 64), 256, 0, stream>>>(mf, Z, ZT, S2, C2, fstep, K);
    phi_kernel<<<(B_ * KP + 255) / 256, 256, 0, stream>>>(S2, C2, cnt, cphi, sphi, rdc, rds);
    gemm1x<<<8 * 4 * 19, 256, 0, stream>>>(dm_h, Z, cphi, sphi, rdc, rds, W);
    gemm2x<<<8 * 19 * 2, 256, 0, stream>>>(W, ZT, rpart);
    norm2_kernel<<<M_, 256, 0, stream>>>(rpart, data, mf, cnt, out);
}

// Round 4
// 125.176 us; speedup vs baseline: 3.8534x; 1.1004x over previous
//
#include <hip/hip_runtime.h>
#include <math.h>

#define B_ 8
#define C_ 64
#define M_ 512            // B_*C_
#define T_ 1200
#define TP 1216           // T_ padded to 64
#define KP 4864           // K padded to 64 (K = 4800)
#define K2P 9728          // 2*KP, interleaved cos/sin rows
#define SPLITK 4
#define KCH (K2P / SPLITK)   // 2432

#ifndef M_PI
#define M_PI 3.14159265358979323846
#endif

typedef _Float16 h8 __attribute__((ext_vector_type(8)));
typedef float f32x4 __attribute__((ext_vector_type(4)));
union H8 { h8 h; float4 v; _Float16 e[8]; };
union HP { _Float16 hh[2]; unsigned u; };
union F4U { float4 v; float f[4]; };

__device__ __forceinline__ float2 cmul(float2 a, float2 b) {
    return make_float2(a.x * b.x - a.y * b.y, a.y * b.x + a.x * b.y);
}

// ---------------- mask detect + convert to float ----------------
__global__ void mask_convert_kernel(const void* __restrict__ mask_raw,
                                    float* __restrict__ mf, int n) {
    __shared__ int s_bad_int, s_bad_flt;
    if (threadIdx.x == 0) { s_bad_int = 0; s_bad_flt = 0; }
    __syncthreads();
    const unsigned int* wi = (const unsigned int*)mask_raw;
    const float* wf = (const float*)mask_raw;
    int nw = n >> 2;
    int badI = 0, badF = 0;
    for (int i = threadIdx.x; i < nw; i += blockDim.x) {
        unsigned int v = wi[i];
        if (v > 1u) badI = 1;
        float f = wf[i];
        if (!(f == 0.0f || f == 1.0f)) badF = 1;
    }
    if (badI) s_bad_int = 1;
    if (badF) s_bad_flt = 1;
    __syncthreads();
    int mode = (!s_bad_int) ? 0 : ((!s_bad_flt) ? 1 : 2);
    for (int i = threadIdx.x; i < n; i += blockDim.x) {
        float v;
        if (mode == 0)      v = (float)((const int*)mask_raw)[i];
        else if (mode == 1) v = ((const float*)mask_raw)[i];
        else                v = (float)((const unsigned char*)mask_raw)[i];
        mf[i] = v;
    }
}

__global__ void cnt_kernel(const float* __restrict__ mf, float* __restrict__ cnt) {
    __shared__ float red[256];
    int b = blockIdx.x;
    float s = 0.f;
    for (int t = threadIdx.x; t < T_; t += 256) s += mf[b * T_ + t];
    red[threadIdx.x] = s; __syncthreads();
    for (int w = 128; w > 0; w >>= 1) {
        if (threadIdx.x < w) red[threadIdx.x] += red[threadIdx.x + w];
        __syncthreads();
    }
    if (threadIdx.x == 0) cnt[b] = red[0];
}

__global__ void zero_kernel(float4* __restrict__ p, long long n) {
    long long i = (long long)blockIdx.x * blockDim.x + threadIdx.x;
    long long stride = (long long)gridDim.x * blockDim.x;
    float4 z = make_float4(0.f, 0.f, 0.f, 0.f);
    for (; i < n; i += stride) p[i] = z;
}

// ---------------- dm_h[bc][TP] = fp16(data*m) ----------------
__global__ void prep_dm_kernel(const float* __restrict__ data, const float* __restrict__ mf,
                               _Float16* __restrict__ dm_h) {
    int idx = blockIdx.x * 256 + threadIdx.x;
    if (idx >= M_ * TP) return;
    int t = idx % TP;
    int bc = idx / TP;
    int b = bc >> 6;
    float v = 0.f;
    if (t < T_) v = data[bc * T_ + t] * mf[b * T_ + t];
    dm_h[idx] = (_Float16)v;
}

// ---------------- rotation tables: e^{i w}, e^{i 16w}, e^{i 64w} (dp->f32) ----------------
__global__ void rotk_kernel(float2* __restrict__ rot1, float2* __restrict__ rot16,
                            float2* __restrict__ rot64, double fstep) {
    int k = blockIdx.x * 256 + threadIdx.x;
    if (k >= KP) return;
    double om = 2.0 * M_PI * (fstep + (double)k * fstep);
    double w = (double)((float)om);   // reference rounds omega to f32
    double s, c;
    sincos(w, &s, &c);         rot1[k]  = make_float2((float)c, (float)s);
    sincos(16.0 * w, &s, &c);  rot16[k] = make_float2((float)c, (float)s);
    sincos(64.0 * w, &s, &c);  rot64[k] = make_float2((float)c, (float)s);
}

// ---------------- basis: Z[2k(+1)][t] (cos/sin interleaved), ZT[t][k2], tau sums ----------------
// All-f32 via composed rotations from the dp-accurate tables.
__global__ __launch_bounds__(256) void basis4_kernel(
    const float* __restrict__ mf,
    const float2* __restrict__ rot1t, const float2* __restrict__ rot16t,
    const float2* __restrict__ rot64t,
    _Float16* __restrict__ Z, _Float16* __restrict__ ZT,
    float* __restrict__ S2, float* __restrict__ C2, int K) {
    __shared__ _Float16 sZ[64 * 138];
    __shared__ float mfS[8][68];
    int k0 = blockIdx.x * 64, t0 = blockIdx.y * 64;
    int tid = threadIdx.x;
    int kk = tid >> 2, tq = tid & 3;
    int k = k0 + kk;
    // stage mf tile [8][64]
    {
        int c = tid & 63, bb = tid >> 6;
        for (int b = bb; b < 8; b += 4) {
            int t = t0 + c;
            mfS[b][c] = (t < T_) ? mf[b * T_ + t] : 0.f;
        }
    }
    float2 r1 = rot1t[k], r16 = rot16t[k], r64 = rot64t[k];
    // base = r1 * r16^tq * r64^a  -> angle w*(64a + 16tq + 1)
    float2 r = r1;
    for (int i = 0; i < tq; i++) r = cmul(r, r16);
    {
        int e = blockIdx.y;
        float2 p = r64;
        while (e) { if (e & 1) r = cmul(r, p); p = cmul(p, p); e >>= 1; }
    }
    bool valid = (k < K);
    float cf[16], sf[16];
#pragma unroll
    for (int e2 = 0; e2 < 16; e2++) {
        int t = t0 + tq * 16 + e2;
        float c = (valid && t < T_) ? r.x : 0.f;
        float s = (valid && t < T_) ? r.y : 0.f;
        cf[e2] = c; sf[e2] = s;
        r = cmul(r, r1);
    }
    __syncthreads();
    // tau sums from LDS-staged mf
    float s2a[B_], c2a[B_];
#pragma unroll
    for (int b = 0; b < B_; b++) { s2a[b] = 0.f; c2a[b] = 0.f; }
#pragma unroll
    for (int b = 0; b < B_; b++) {
#pragma unroll
        for (int q = 0; q < 4; q++) {
            F4U mv; mv.v = *(const float4*)&mfS[b][tq * 16 + q * 4];
#pragma unroll
            for (int e2 = 0; e2 < 4; e2++) {
                int i = q * 4 + e2;
                float c = cf[i], s = sf[i], m = mv.f[e2];
                s2a[b] = fmaf(m, 2.f * s * c, s2a[b]);
                c2a[b] = fmaf(m, (c - s) * (c + s), c2a[b]);
            }
        }
    }
#pragma unroll
    for (int b = 0; b < B_; b++) {
        s2a[b] += __shfl_xor(s2a[b], 1); s2a[b] += __shfl_xor(s2a[b], 2);
        c2a[b] += __shfl_xor(c2a[b], 1); c2a[b] += __shfl_xor(c2a[b], 2);
    }
    if (tq == 0 && valid) {
#pragma unroll
        for (int b = 0; b < B_; b++) {
            atomicAdd(&S2[b * KP + k], s2a[b]);
            atomicAdd(&C2[b * KP + k], c2a[b]);
        }
    }
    // Z rows 2k (cos), 2k+1 (sin)
    H8 pc0, pc1, ps0, ps1;
#pragma unroll
    for (int e2 = 0; e2 < 8; e2++) {
        pc0.e[e2] = (_Float16)cf[e2];  pc1.e[e2] = (_Float16)cf[e2 + 8];
        ps0.e[e2] = (_Float16)sf[e2];  ps1.e[e2] = (_Float16)sf[e2 + 8];
    }
    size_t zoff = (size_t)(2 * k) * TP + t0 + tq * 16;
    *(float4*)&Z[zoff] = pc0.v;       *(float4*)&Z[zoff + 8] = pc1.v;
    *(float4*)&Z[zoff + TP] = ps0.v;  *(float4*)&Z[zoff + TP + 8] = ps1.v;
    // LDS transpose to ZT[t][k2]
#pragma unroll
    for (int e2 = 0; e2 < 16; e2++) {
        HP pk; pk.hh[0] = (_Float16)cf[e2]; pk.hh[1] = (_Float16)sf[e2];
        *(unsigned*)&sZ[(tq * 16 + e2) * 138 + 2 * kk] = pk.u;
    }
    __syncthreads();
    int tl = tid >> 2, kq = tid & 3;
    float4 o0 = *(float4*)&sZ[tl * 138 + kq * 32];
    float4 o1 = *(float4*)&sZ[tl * 138 + kq * 32 + 8];
    float4 o2 = *(float4*)&sZ[tl * 138 + kq * 32 + 16];
    float4 o3 = *(float4*)&sZ[tl * 138 + kq * 32 + 24];
    size_t toff = (size_t)(t0 + tl) * K2P + 2 * k0 + kq * 32;
    *(float4*)&ZT[toff] = o0;       *(float4*)&ZT[toff + 8] = o1;
    *(float4*)&ZT[toff + 16] = o2;  *(float4*)&ZT[toff + 24] = o3;
}

// ---------------- phi + reciprocal denominators ----------------
__global__ void phi_kernel(const float* __restrict__ S2, const float* __restrict__ C2,
                           const float* __restrict__ cnt,
                           float* __restrict__ cphi, float* __restrict__ sphi,
                           float* __restrict__ rdc, float* __restrict__ rds) {
    int idx = blockIdx.x * 256 + threadIdx.x;
    if (idx >= B_ * KP) return;
    int b = idx / KP;
    float s2 = S2[idx], c2 = C2[idx];
    float phi = 0.5f * atan2f(s2, c2);
    float cp = cosf(phi), sp = sinf(phi);
    float cn = cnt[b];
    float A = 0.5f * (cn + c2), D = 0.5f * (cn - c2), E = 0.5f * s2;
    cphi[idx] = cp; sphi[idx] = sp;
    rdc[idx] = 1.f / (cp * cp * A + 2.f * cp * sp * E + sp * sp * D);
    rds[idx] = 1.f / (sp * sp * A - 2.f * cp * sp * E + cp * cp * D);
}

// swizzled LDS offset (halves): row stride 64 halves, 16B chunk index XOR'd with row&7
__device__ __forceinline__ int swz(int row, int c16) {
    return row * 64 + ((c16 ^ (row & 7)) << 3);
}

// ---------------- GEMM1: W[bc][k2] = sum_t dm[bc][t] * Z[k2][t], fused LS-combine ----------------
__global__ __launch_bounds__(256) void gemm1x(
    const _Float16* __restrict__ dm, const _Float16* __restrict__ Z,
    const float* __restrict__ cphi, const float* __restrict__ sphi,
    const float* __restrict__ rdc, const float* __restrict__ rds,
    _Float16* __restrict__ W) {
    __shared__ _Float16 sA[128 * 64], sB[64 * 64];
    int bx = blockIdx.x;                       // 608 = 8 * (4 * 19)
    int xcd = bx & 7, rem = bx >> 3;
    int mt = rem & 3, g = rem >> 2;            // g 0..18
    int nt = xcd + 8 * g;                      // 0..151; same nt -> same XCD
    int m0 = mt * 128, n0 = nt * 64;
    int tid = threadIdx.x, lane = tid & 63, wv = tid >> 6;
    f32x4 acc[2][4];
#pragma unroll
    for (int i = 0; i < 2; i++)
#pragma unroll
        for (int j = 0; j < 4; j++) acc[i][j] = (f32x4){0.f, 0.f, 0.f, 0.f};
    int ar = tid >> 1, ah = tid & 1;
    int br = tid >> 2, bq = tid & 3;
    const _Float16* gA = dm + (size_t)(m0 + ar) * TP;
    const _Float16* gB = Z + (size_t)(n0 + br) * TP;
    for (int rc = 0; rc < TP; rc += 64) {
        float4 va0 = *(const float4*)&gA[rc + (ah * 4 + 0) * 8];
        float4 va1 = *(const float4*)&gA[rc + (ah * 4 + 1) * 8];
        float4 va2 = *(const float4*)&gA[rc + (ah * 4 + 2) * 8];
        float4 va3 = *(const float4*)&gA[rc + (ah * 4 + 3) * 8];
        float4 vb0 = *(const float4*)&gB[rc + (bq * 2 + 0) * 8];
        float4 vb1 = *(const float4*)&gB[rc + (bq * 2 + 1) * 8];
        __syncthreads();
        *(float4*)&sA[swz(ar, ah * 4 + 0)] = va0;
        *(float4*)&sA[swz(ar, ah * 4 + 1)] = va1;
        *(float4*)&sA[swz(ar, ah * 4 + 2)] = va2;
        *(float4*)&sA[swz(ar, ah * 4 + 3)] = va3;
        *(float4*)&sB[swz(br, bq * 2 + 0)] = vb0;
        *(float4*)&sB[swz(br, bq * 2 + 1)] = vb1;
        __syncthreads();
#pragma unroll
        for (int ks = 0; ks < 2; ks++) {
            int c16 = ks * 4 + (lane >> 4);
            int r0 = 32 * wv + (lane & 15);
            int r1 = r0 + 16;
            h8 a0 = *(h8*)&sA[swz(r0, c16)];
            h8 a1 = *(h8*)&sA[swz(r1, c16)];
#pragma unroll
            for (int j = 0; j < 4; j++) {
                int rb = 16 * j + (lane & 15);
                h8 bfr = *(h8*)&sB[swz(rb, c16)];
                acc[0][j] = __builtin_amdgcn_mfma_f32_16x16x32_f16(a0, bfr, acc[0][j], 0, 0, 0);
                acc[1][j] = __builtin_amdgcn_mfma_f32_16x16x32_f16(a1, bfr, acc[1][j], 0, 0, 0);
            }
        }
    }
    // epilogue: Lomb-Scargle combine in-register, write fp16 W[bc][k2]
    int colb = lane & 15;
    int par = colb & 1;                        // 0: cos row (P->U), 1: sin row (Q->V)
#pragma unroll
    for (int i = 0; i < 2; i++) {
        int mbase = m0 + 32 * wv + 16 * i + ((lane >> 4) << 2);
        int b = mbase >> 6;
#pragma unroll
        for (int j = 0; j < 4; j++) {
            int k2 = n0 + 16 * j + colb;
            int kidx = b * KP + (k2 >> 1);
            float cp = cphi[kidx], sp = sphi[kidx];
            float rc_ = rdc[kidx], rs_ = rds[kidx];
            f32x4 own = acc[i][j];
            f32x4 oth;
#pragma unroll
            for (int r = 0; r < 4; r++) oth[r] = __shfl_xor(own[r], 1);
#pragma unroll
            for (int r = 0; r < 4; r++) {
                float p = par ? oth[r] : own[r];
                float q = par ? own[r] : oth[r];
                float cc = (cp * p + sp * q) * rc_;
                float sc = (cp * q - sp * p) * rs_;
                float val = par ? (sp * cc + cp * sc) : (cp * cc - sp * sc);
                W[(size_t)(mbase + r) * K2P + k2] = (_Float16)val;
            }
        }
    }
}

// ---------------- GEMM2: rpart[sk][bc][t] = sum_{k2 chunk} W[bc][k2] * ZT[t][k2] ----------------
__global__ __launch_bounds__(256) void gemm2x(
    const _Float16* __restrict__ W, const _Float16* __restrict__ ZT,
    float* __restrict__ rpart) {
    __shared__ _Float16 sA[128 * 64], sB[64 * 64];
    int bx = blockIdx.x;                       // 304 = 8 * (19 * 2)
    int xcd = bx & 7, rem = bx >> 3;
    int nt = rem % 19, q = rem / 19;
    int msk = xcd + 8 * q;                     // 0..15; same (mt,sk) -> same XCD
    int mt = msk & 3, sk = msk >> 2;
    int m0 = mt * 128, t0 = nt * 64, kbase = sk * KCH;
    int tid = threadIdx.x, lane = tid & 63, wv = tid >> 6;
    f32x4 acc[2][4];
#pragma unroll
    for (int i = 0; i < 2; i++)
#pragma unroll
        for (int j = 0; j < 4; j++) acc[i][j] = (f32x4){0.f, 0.f, 0.f, 0.f};
    int ar = tid >> 1, ah = tid & 1;
    int br = tid >> 2, bq = tid & 3;
    const _Float16* gA = W + (size_t)(m0 + ar) * K2P + kbase;
    const _Float16* gB = ZT + (size_t)(t0 + br) * K2P + kbase;
    for (int rc = 0; rc < KCH; rc += 64) {
        float4 va0 = *(const float4*)&gA[rc + (ah * 4 + 0) * 8];
        float4 va1 = *(const float4*)&gA[rc + (ah * 4 + 1) * 8];
        float4 va2 = *(const float4*)&gA[rc + (ah * 4 + 2) * 8];
        float4 va3 = *(const float4*)&gA[rc + (ah * 4 + 3) * 8];
        float4 vb0 = *(const float4*)&gB[rc + (bq * 2 + 0) * 8];
        float4 vb1 = *(const float4*)&gB[rc + (bq * 2 + 1) * 8];
        __syncthreads();
        *(float4*)&sA[swz(ar, ah * 4 + 0)] = va0;
        *(float4*)&sA[swz(ar, ah * 4 + 1)] = va1;
        *(float4*)&sA[swz(ar, ah * 4 + 2)] = va2;
        *(float4*)&sA[swz(ar, ah * 4 + 3)] = va3;
        *(float4*)&sB[swz(br, bq * 2 + 0)] = vb0;
        *(float4*)&sB[swz(br, bq * 2 + 1)] = vb1;
        __syncthreads();
#pragma unroll
        for (int ks = 0; ks < 2; ks++) {
            int c16 = ks * 4 + (lane >> 4);
            int r0 = 32 * wv + (lane & 15);
            int r1 = r0 + 16;
            h8 a0 = *(h8*)&sA[swz(r0, c16)];
            h8 a1 = *(h8*)&sA[swz(r1, c16)];
#pragma unroll
            for (int j = 0; j < 4; j++) {
                int rb = 16 * j + (lane & 15);
                h8 bfr = *(h8*)&sB[swz(rb, c16)];
                acc[0][j] = __builtin_amdgcn_mfma_f32_16x16x32_f16(a0, bfr, acc[0][j], 0, 0, 0);
                acc[1][j] = __builtin_amdgcn_mfma_f32_16x16x32_f16(a1, bfr, acc[1][j], 0, 0, 0);
            }
        }
    }
#pragma unroll
    for (int i = 0; i < 2; i++) {
        int mbase = m0 + 32 * wv + 16 * i + ((lane >> 4) << 2);
#pragma unroll
        for (int j = 0; j < 4; j++) {
            int t = t0 + 16 * j + (lane & 15);
#pragma unroll
            for (int r = 0; r < 4; r++)
                rpart[((size_t)sk * M_ + mbase + r) * TP + t] = acc[i][j][r];
        }
    }
}

// ---------------- normalize + select (LDS-cached recon row) ----------------
__global__ void norm2_kernel(const float* __restrict__ rpart, const float* __restrict__ data,
                             const float* __restrict__ mf, const float* __restrict__ cnt,
                             float* __restrict__ out) {
    __shared__ float rsum[T_];
    __shared__ float4 red[256];
    __shared__ float s_scale;
    int bc = blockIdx.x, b = bc >> 6;
    const size_t rbase = (size_t)bc * TP;
    const size_t dbase = (size_t)bc * T_;
    const size_t rstr = (size_t)M_ * TP;
    float sr = 0.f, srr = 0.f, sd = 0.f, sdd = 0.f;
    for (int t = threadIdx.x; t < T_; t += 256) {
        float r = rpart[rbase + t] + rpart[rstr + rbase + t]
                + rpart[2 * rstr + rbase + t] + rpart[3 * rstr + rbase + t];
        rsum[t] = r;
        float x = data[dbase + t], m = mf[b * T_ + t];
        sr += r; srr += r * r; sd += x * m; sdd += x * x * m;
    }
    red[threadIdx.x] = make_float4(sr, srr, sd, sdd);
    __syncthreads();
    for (int w = 128; w > 0; w >>= 1) {
        if (threadIdx.x < w) {
            float4 a = red[threadIdx.x], c = red[threadIdx.x + w];
            red[threadIdx.x] = make_float4(a.x + c.x, a.y + c.y, a.z + c.z, a.w + c.w);
        }
        __syncthreads();
    }
    if (threadIdx.x == 0) {
        float4 v = red[0];
        float cn = cnt[b];
        float varr = (v.y - v.x * v.x / (float)T_) / (float)(T_ - 1);
        float vard = (v.w - v.z * v.z / cn) / (cn - 1.f);
        s_scale = sqrtf(vard / varr);
    }
    __syncthreads();
    float scale = s_scale;
    for (int t = threadIdx.x; t < T_; t += 256) {
        float m = mf[b * T_ + t];
        out[dbase + t] = (m > 0.5f) ? data[dbase + t] : rsum[t] * scale;
    }
}

extern "C" void kernel_launch(void* const* d_in, const int* in_sizes, int n_in,
                              void* d_out, int out_size, void* d_ws, size_t ws_size,
                              hipStream_t stream) {
    const float* data = (const float*)d_in[0];
    const void* mask = d_in[1];
    float* out = (float*)d_out;

    const double timespan = 1.0 * (T_ + 1) - 1.0;               // 1200
    const double fstep = 1.0 / (timespan * 8.0);                // OSFREQ = 8
    const double stop = (1.0 * (double)T_) / (2.0 * timespan) + fstep;
    const int K = (int)ceil((stop - fstep) / fstep);            // 4800 (or 4801)

    char* w = (char*)d_ws;
    auto alloc = [&](size_t nbytes) {
        char* p = w;
        w += ((nbytes + 255) / 256) * 256;
        return p;
    };
    float*     mf    = (float*)    alloc((size_t)B_ * T_ * 4);
    float*     cnt   = (float*)    alloc(B_ * 4);
    char* zstart = w;
    float*     S2    = (float*)    alloc((size_t)B_ * KP * 4);
    float*     C2    = (float*)    alloc((size_t)B_ * KP * 4);
    char* zend = w;
    float*     cphi  = (float*)    alloc((size_t)B_ * KP * 4);
    float*     sphi  = (float*)    alloc((size_t)B_ * KP * 4);
    float*     rdc   = (float*)    alloc((size_t)B_ * KP * 4);
    float*     rds   = (float*)    alloc((size_t)B_ * KP * 4);
    float2*    rot1  = (float2*)   alloc((size_t)KP * 8);
    float2*    rot16 = (float2*)   alloc((size_t)KP * 8);
    float2*    rot64 = (float2*)   alloc((size_t)KP * 8);
    _Float16*  dm_h  = (_Float16*) alloc((size_t)M_ * TP * 2);
    _Float16*  Z     = (_Float16*) alloc((size_t)K2P * TP * 2);
    _Float16*  ZT    = (_Float16*) alloc((size_t)TP * K2P * 2);
    _Float16*  W     = (_Float16*) alloc((size_t)M_ * K2P * 2);
    float*     rpart = (float*)    alloc((size_t)SPLITK * M_ * TP * 4);
    (void)ws_size; (void)in_sizes; (void)n_in; (void)out_size;

    mask_convert_kernel<<<1, 256, 0, stream>>>(mask, mf, B_ * T_);
    cnt_kernel<<<B_, 256, 0, stream>>>(mf, cnt);
    long long zn = (long long)(zend - zstart) / 16;
    zero_kernel<<<96, 256, 0, stream>>>((float4*)zstart, zn);
    rotk_kernel<<<(KP + 255) / 256, 256, 0, stream>>>(rot1, rot16, rot64, fstep);
    prep_dm_kernel<<<(M_ * TP + 255) / 256, 256, 0, stream>>>(data, mf, dm_h);
    basis4_kernel<<<dim3(KP / 64, TP / 64), 256, 0, stream>>>(mf, rot1, rot16, rot64,
                                                              Z, ZT, S2, C2, K);
    phi_kernel<<<(B_ * KP + 255) / 256, 256, 0, stream>>>(S2, C2, cnt, cphi, sphi, rdc, rds);
    gemm1x<<<8 * 4 * 19, 256, 0, stream>>>(dm_h, Z, cphi, sphi, rdc, rds, W);
    gemm2x<<<8 * 19 * 2, 256, 0, stream>>>(W, ZT, rpart);
    norm2_kernel<<<M_, 256, 0, stream>>>(rpart, data, mf, cnt, out);
}

// Round 5
// 115.251 us; speedup vs baseline: 4.1853x; 1.0861x over previous
//
#include <hip/hip_runtime.h>
#include <math.h>

#define B_ 8
#define C_ 64
#define M_ 512            // B_*C_
#define T_ 1200
#define TP2 1280          // T padded to 128
#define KP 4864           // K padded (K = 4800)
#define K2P 9728          // 2*KP interleaved cos/sin
#define SPLITK 8
#define KCH 1216          // K2P/SPLITK
#define NST1 20           // TP2/64 k-steps (gemm1 reduction = t)
#define NST2 19           // KCH/64 k-steps (gemm2 reduction = k2)

#ifndef M_PI
#define M_PI 3.14159265358979323846
#endif

typedef _Float16 h8 __attribute__((ext_vector_type(8)));
typedef float f32x16 __attribute__((ext_vector_type(16)));
union H8 { h8 h; float4 v; _Float16 e[8]; };
union HP { _Float16 hh[2]; unsigned u; };
union F4U { float4 v; float f[4]; };

#define Z16v {0.f,0.f,0.f,0.f,0.f,0.f,0.f,0.f,0.f,0.f,0.f,0.f,0.f,0.f,0.f,0.f}
#define MFMA32(a, b, c) __builtin_amdgcn_mfma_f32_32x32x16_f16(a, b, c, 0, 0, 0)

__device__ __forceinline__ float2 cmul(float2 a, float2 b) {
    return make_float2(a.x * b.x - a.y * b.y, a.y * b.x + a.x * b.y);
}

// async global->LDS, 16B per lane, linear dest (wave-uniform base + lane*16)
__device__ __forceinline__ void gload16(const void* g, void* l) {
    __builtin_amdgcn_global_load_lds(
        (const __attribute__((address_space(1))) unsigned int*)g,
        (__attribute__((address_space(3))) unsigned int*)l, 16, 0, 0);
}

// ---------------- setup: mask convert + cnt (block 0), rot tables (blocks 1..19) ----------------
__global__ void setup_kernel(const void* __restrict__ mask_raw, float* __restrict__ mf,
                             float* __restrict__ cnt,
                             float2* __restrict__ rot1, float2* __restrict__ rot8,
                             float2* __restrict__ rot64, double fstep) {
    if (blockIdx.x == 0) {
        __shared__ int s_bad_int, s_bad_flt;
        __shared__ float red[256];
        int tid = threadIdx.x;
        if (tid == 0) { s_bad_int = 0; s_bad_flt = 0; }
        __syncthreads();
        const int n = B_ * T_;
        const unsigned int* wi = (const unsigned int*)mask_raw;
        const float* wf = (const float*)mask_raw;
        int nw = n >> 2;
        int badI = 0, badF = 0;
        for (int i = tid; i < nw; i += 256) {
            unsigned int v = wi[i];
            if (v > 1u) badI = 1;
            float f = wf[i];
            if (!(f == 0.0f || f == 1.0f)) badF = 1;
        }
        if (badI) s_bad_int = 1;
        if (badF) s_bad_flt = 1;
        __syncthreads();
        int mode = (!s_bad_int) ? 0 : ((!s_bad_flt) ? 1 : 2);
        for (int i = tid; i < n; i += 256) {
            float v;
            if (mode == 0)      v = (float)((const int*)mask_raw)[i];
            else if (mode == 1) v = ((const float*)mask_raw)[i];
            else                v = (float)((const unsigned char*)mask_raw)[i];
            mf[i] = v;
        }
        __syncthreads();
        for (int b = 0; b < B_; b++) {
            float s = 0.f;
            for (int t = tid; t < T_; t += 256) s += mf[b * T_ + t];
            red[tid] = s; __syncthreads();
            for (int w = 128; w > 0; w >>= 1) {
                if (tid < w) red[tid] += red[tid + w];
                __syncthreads();
            }
            if (tid == 0) cnt[b] = red[0];
            __syncthreads();
        }
    } else {
        int k = (blockIdx.x - 1) * 256 + threadIdx.x;   // < KP = 4864
        double om = 2.0 * M_PI * (fstep + (double)k * fstep);
        double w = (double)((float)om);   // reference rounds omega to f32
        double s, c;
        sincos(w, &s, &c);         rot1[k]  = make_float2((float)c, (float)s);
        sincos(8.0 * w, &s, &c);   rot8[k]  = make_float2((float)c, (float)s);
        sincos(64.0 * w, &s, &c);  rot64[k] = make_float2((float)c, (float)s);
    }
}

// ---------------- basis: per-k-stripe full-T loop; Z, ZT, tau+phi fused; prep_dm folded ----------------
__global__ __launch_bounds__(256) void basisC_kernel(
    const float* __restrict__ mf, const float* __restrict__ data,
    const float* __restrict__ cnt,
    const float2* __restrict__ rot1t, const float2* __restrict__ rot8t,
    const float2* __restrict__ rot64t,
    _Float16* __restrict__ Zb, _Float16* __restrict__ ZT, _Float16* __restrict__ dm,
    float* __restrict__ cphi, float* __restrict__ sphi,
    float* __restrict__ rdcv, float* __restrict__ rdsv, int K) {
    int tid = threadIdx.x;
    if (blockIdx.x >= 152) {
        // prep_dm: dm[bc][TP2] = f16(data*m)
        int bid = blockIdx.x - 152;   // 0..9
        for (int it = 0; it < 32; it++) {
            int idx8 = it * 2560 + bid * 256 + tid;   // 81920 chunks of 8 halves
            int base = idx8 * 8;
            int t = base % TP2, bc = base / TP2;
            H8 o;
            if (t < T_) {
                int b = bc >> 6;
                const float* dp = &data[bc * T_ + t];
                const float* mp = &mf[b * T_ + t];
                F4U d0, d1, m0v, m1v;
                d0.v = *(const float4*)dp; d1.v = *(const float4*)(dp + 4);
                m0v.v = *(const float4*)mp; m1v.v = *(const float4*)(mp + 4);
#pragma unroll
                for (int e = 0; e < 4; e++) {
                    o.e[e] = (_Float16)(d0.f[e] * m0v.f[e]);
                    o.e[e + 4] = (_Float16)(d1.f[e] * m1v.f[e]);
                }
            } else {
#pragma unroll
                for (int e = 0; e < 8; e++) o.e[e] = (_Float16)0.f;
            }
            *(float4*)&dm[base] = o.v;
        }
        return;
    }
    __shared__ float mfS[8][72];
    __shared__ _Float16 sZ[64 * 72];
    int kk = tid >> 3, tq = tid & 7;           // 32 k x 8 t-groups
    int k = blockIdx.x * 32 + kk;
    bool valid = (k < K);
    float2 r1 = rot1t[k], r8 = rot8t[k], r64 = rot64t[k];
    float2 rtq = make_float2(1.f, 0.f);
    {
        float2 p = r8;
        if (tq & 1) rtq = cmul(rtq, p);
        p = cmul(p, p);
        if (tq & 2) rtq = cmul(rtq, p);
        p = cmul(p, p);
        if (tq & 4) rtq = cmul(rtq, p);
    }
    float2 rstart = cmul(r1, rtq);             // angle w*(8*tq + 1)
    float2 racc = make_float2(1.f, 0.f);       // w*64*tile
    float s2a[8], c2a[8];
#pragma unroll
    for (int b = 0; b < 8; b++) { s2a[b] = 0.f; c2a[b] = 0.f; }
    for (int a = 0; a < TP2 / 64; a++) {
        int t0 = a * 64;
        __syncthreads();   // previous tile's LDS consumers done
#pragma unroll
        for (int u = 0; u < 2; u++) {
            int idx = u * 256 + tid;
            int b = idx >> 6, c = idx & 63;
            int t = t0 + c;
            mfS[b][c] = (t < T_) ? mf[b * T_ + t] : 0.f;
        }
        float2 rb = cmul(rstart, racc);
        float cf[8], sf[8];
#pragma unroll
        for (int e = 0; e < 8; e++) {
            int t = t0 + tq * 8 + e;
            bool ok = valid && (t < T_);
            cf[e] = ok ? rb.x : 0.f;
            sf[e] = ok ? rb.y : 0.f;
            rb = cmul(rb, r1);
        }
#pragma unroll
        for (int e = 0; e < 8; e++) {
            HP pk; pk.hh[0] = (_Float16)cf[e]; pk.hh[1] = (_Float16)sf[e];
            *(unsigned*)&sZ[(tq * 8 + e) * 72 + 2 * kk] = pk.u;
        }
        __syncthreads();   // mfS + sZ visible
        // tau sums
#pragma unroll
        for (int b = 0; b < 8; b++) {
            F4U u0, u1;
            u0.v = *(const float4*)&mfS[b][tq * 8];
            u1.v = *(const float4*)&mfS[b][tq * 8 + 4];
#pragma unroll
            for (int e = 0; e < 8; e++) {
                float m = (e < 4) ? u0.f[e] : u1.f[e - 4];
                s2a[b] = fmaf(m, 2.f * sf[e] * cf[e], s2a[b]);
                c2a[b] = fmaf(m, (cf[e] - sf[e]) * (cf[e] + sf[e]), c2a[b]);
            }
        }
        // Z rows 2k (cos), 2k+1 (sin)
        H8 hc, hs;
#pragma unroll
        for (int e = 0; e < 8; e++) { hc.e[e] = (_Float16)cf[e]; hs.e[e] = (_Float16)sf[e]; }
        size_t zoff = (size_t)(2 * k) * TP2 + t0 + tq * 8;
        *(float4*)&Zb[zoff] = hc.v;
        *(float4*)&Zb[zoff + TP2] = hs.v;
        // ZT[t][k2] from sZ
        int row = tid >> 2, q = tid & 3;
        float4 z0 = *(const float4*)&sZ[row * 72 + q * 16];
        float4 z1 = *(const float4*)&sZ[row * 72 + q * 16 + 8];
        size_t toff = (size_t)(t0 + row) * K2P + (size_t)blockIdx.x * 64 + q * 16;
        *(float4*)&ZT[toff] = z0;
        *(float4*)&ZT[toff + 8] = z1;
        racc = cmul(racc, r64);
    }
    // reduce tau over the 8 tq lanes, then phi (folded)
#pragma unroll
    for (int b = 0; b < 8; b++) {
        s2a[b] += __shfl_xor(s2a[b], 1); s2a[b] += __shfl_xor(s2a[b], 2); s2a[b] += __shfl_xor(s2a[b], 4);
        c2a[b] += __shfl_xor(c2a[b], 1); c2a[b] += __shfl_xor(c2a[b], 2); c2a[b] += __shfl_xor(c2a[b], 4);
    }
    if (tq == 0) {
#pragma unroll
        for (int b = 0; b < 8; b++) {
            float s2 = s2a[b], c2 = c2a[b];
            float phi = 0.5f * atan2f(s2, c2);
            float cp = cosf(phi), sp = sinf(phi);
            float cn = cnt[b];
            float A = 0.5f * (cn + c2), D = 0.5f * (cn - c2), E = 0.5f * s2;
            int kidx = b * KP + k;
            cphi[kidx] = cp; sphi[kidx] = sp;
            rdcv[kidx] = 1.f / (cp * cp * A + 2.f * cp * sp * E + sp * sp * D);
            rdsv[kidx] = 1.f / (sp * sp * A - 2.f * cp * sp * E + cp * cp * D);
        }
    }
}

// shared 128x128 MFMA core pieces --------------------------------------------
// LDS tile: 128 rows x 64 halves, 16B chunks; physical chunk p at row r holds
// logical chunk p^(r&7). Staging: linear dest, inverse-swizzled global source.
#define KSTEP(LA, LB)                                                          \
    _Pragma("unroll")                                                          \
    for (int kc = 0; kc < 4; kc++) {                                           \
        int c = kc * 2 + kg;                                                   \
        h8 a0 = *(const h8*)((LA) + ((r0 * 8 + (c ^ x)) << 4));                \
        h8 a1 = *(const h8*)((LA) + (((r0 + 32) * 8 + (c ^ x)) << 4));         \
        h8 b0 = *(const h8*)((LB) + ((q0 * 8 + (c ^ x)) << 4));                \
        h8 b1 = *(const h8*)((LB) + (((q0 + 32) * 8 + (c ^ x)) << 4));         \
        acc00 = MFMA32(a0, b0, acc00);                                         \
        acc01 = MFMA32(a0, b1, acc01);                                         \
        acc10 = MFMA32(a1, b0, acc10);                                         \
        acc11 = MFMA32(a1, b1, acc11);                                         \
    }

// ---------------- GEMM1: W[m][k2] = sum_t dm[m][t] * Z[k2][t], fused LS-combine ----------------
__global__ __launch_bounds__(256, 2) void gemm1x(
    const _Float16* __restrict__ dm, const _Float16* __restrict__ Zb,
    const float* __restrict__ cphi, const float* __restrict__ sphi,
    const float* __restrict__ rdc, const float* __restrict__ rds,
    _Float16* __restrict__ Wout) {
    __shared__ _Float16 lds[32768];   // 64KB: 2 bufs x (A 16KB | B 16KB)
    char* ldsb = (char*)lds;
    int bx = blockIdx.x;                    // 304 = 8 XCD * 38
    int g = (bx & 7) * 38 + (bx >> 3);      // bijective, XCD-chunked
    int mt = g & 3, nt = g >> 2;
    int m0 = mt * 128, n0 = nt * 128;
    int tid = threadIdx.x, lane = tid & 63, wv = tid >> 6;
    int ra = lane & 31, kg = lane >> 5, x = ra & 7;
    int wm = (wv & 1) * 64, wn = (wv >> 1) * 64;
    int r0 = wm + ra, q0 = wn + ra;
    f32x16 acc00 = Z16v, acc01 = Z16v, acc10 = Z16v, acc11 = Z16v;
    int sA[4], sL[4];
#pragma unroll
    for (int i = 0; i < 4; i++) {
        int g8 = i * 256 + tid;
        int r = g8 >> 3, c = g8 & 7;
        sA[i] = r * 2560 + ((c ^ (r & 7)) << 4);
        sL[i] = g8 << 4;
    }
    const char* pA = (const char*)dm + (size_t)m0 * 2560;
    const char* pB = (const char*)Zb + (size_t)n0 * 2560;
#pragma unroll
    for (int i = 0; i < 4; i++) gload16(pA + sA[i], ldsb + sL[i]);
#pragma unroll
    for (int i = 0; i < 4; i++) gload16(pB + sA[i], ldsb + 16384 + sL[i]);
    __syncthreads();
    int cur = 0;
    for (int step = 0; step < NST1; step++) {
        if (step + 1 < NST1) {
            int rc = (step + 1) << 7;
            char* lb = ldsb + (cur ^ 1) * 32768;
#pragma unroll
            for (int i = 0; i < 4; i++) gload16(pA + rc + sA[i], lb + sL[i]);
#pragma unroll
            for (int i = 0; i < 4; i++) gload16(pB + rc + sA[i], lb + 16384 + sL[i]);
        }
        const char* LA = ldsb + cur * 32768;
        const char* LB = LA + 16384;
        KSTEP(LA, LB);
        __syncthreads();
        cur ^= 1;
    }
    // epilogue: Lomb-Scargle combine in-register (P,Q in adjacent lanes), write f16 W
    int bb = (m0 + wm) >> 6;
    int colk = lane & 31, rb4 = (lane >> 5) * 4;
#define EPI1(ACC, I, J) {                                                      \
        int k2 = n0 + wn + 32 * (J) + colk;                                    \
        int kidx = bb * KP + (k2 >> 1);                                        \
        float cp = cphi[kidx], sp = sphi[kidx];                                \
        float rc_ = rdc[kidx], rs_ = rds[kidx];                                \
        int par = k2 & 1;                                                      \
        _Pragma("unroll")                                                      \
        for (int reg = 0; reg < 16; reg++) {                                   \
            float own = (ACC)[reg];                                            \
            float oth = __shfl_xor(own, 1);                                    \
            float p = par ? oth : own, q = par ? own : oth;                    \
            float cc = (cp * p + sp * q) * rc_;                                \
            float sc = (cp * q - sp * p) * rs_;                                \
            float val = par ? (sp * cc + cp * sc) : (cp * cc - sp * sc);       \
            int row = m0 + wm + 32 * (I) + rb4 + (reg & 3) + 8 * (reg >> 2);   \
            Wout[(size_t)row * K2P + k2] = (_Float16)val;                      \
        } }
    EPI1(acc00, 0, 0); EPI1(acc01, 0, 1); EPI1(acc10, 1, 0); EPI1(acc11, 1, 1);
#undef EPI1
}

// ---------------- GEMM2: rpart[sk][m][t] = sum_{k2 in chunk} W[m][k2] * ZT[t][k2] ----------------
__global__ __launch_bounds__(256, 2) void gemm2x(
    const _Float16* __restrict__ Wm, const _Float16* __restrict__ ZT,
    float* __restrict__ rpart) {
    __shared__ _Float16 lds[32768];
    char* ldsb = (char*)lds;
    int bx = blockIdx.x;                 // 320 = 8 XCD * 40; one sk per XCD
    int sk = bx & 7;
    int idx = bx >> 3;                   // 0..39
    int nt = idx >> 2, mt = idx & 3;
    int m0 = mt * 128, t0 = nt * 128;
    int tid = threadIdx.x, lane = tid & 63, wv = tid >> 6;
    int ra = lane & 31, kg = lane >> 5, x = ra & 7;
    int wm = (wv & 1) * 64, wn = (wv >> 1) * 64;
    int r0 = wm + ra, q0 = wn + ra;
    f32x16 acc00 = Z16v, acc01 = Z16v, acc10 = Z16v, acc11 = Z16v;
    int sA[4], sL[4];
#pragma unroll
    for (int i = 0; i < 4; i++) {
        int g8 = i * 256 + tid;
        int r = g8 >> 3, c = g8 & 7;
        sA[i] = r * 19456 + ((c ^ (r & 7)) << 4);
        sL[i] = g8 << 4;
    }
    const char* pA = (const char*)Wm + (size_t)m0 * 19456 + sk * 2432;
    const char* pB = (const char*)ZT + (size_t)t0 * 19456 + sk * 2432;
#pragma unroll
    for (int i = 0; i < 4; i++) gload16(pA + sA[i], ldsb + sL[i]);
#pragma unroll
    for (int i = 0; i < 4; i++) gload16(pB + sA[i], ldsb + 16384 + sL[i]);
    __syncthreads();
    int cur = 0;
    for (int step = 0; step < NST2; step++) {
        if (step + 1 < NST2) {
            int rc = (step + 1) << 7;
            char* lb = ldsb + (cur ^ 1) * 32768;
#pragma unroll
            for (int i = 0; i < 4; i++) gload16(pA + rc + sA[i], lb + sL[i]);
#pragma unroll
            for (int i = 0; i < 4; i++) gload16(pB + rc + sA[i], lb + 16384 + sL[i]);
        }
        const char* LA = ldsb + cur * 32768;
        const char* LB = LA + 16384;
        KSTEP(LA, LB);
        __syncthreads();
        cur ^= 1;
    }
    int colk = lane & 31, rb4 = (lane >> 5) * 4;
#define EPI2(ACC, I, J) {                                                      \
        int t = t0 + wn + 32 * (J) + colk;                                     \
        _Pragma("unroll")                                                      \
        for (int reg = 0; reg < 16; reg++) {                                   \
            int row = m0 + wm + 32 * (I) + rb4 + (reg & 3) + 8 * (reg >> 2);   \
            rpart[(size_t)(sk * M_ + row) * TP2 + t] = (ACC)[reg];             \
        } }
    EPI2(acc00, 0, 0); EPI2(acc01, 0, 1); EPI2(acc10, 1, 0); EPI2(acc11, 1, 1);
#undef EPI2
}

// ---------------- normalize + select ----------------
__global__ void norm3_kernel(const float* __restrict__ rpart, const float* __restrict__ data,
                             const float* __restrict__ mf, const float* __restrict__ cnt,
                             float* __restrict__ out) {
    __shared__ float rsum[T_];
    __shared__ float4 red[256];
    __shared__ float s_scale;
    int bc = blockIdx.x, b = bc >> 6;
    const size_t rbase = (size_t)bc * TP2;
    const size_t dbase = (size_t)bc * T_;
    const size_t rstr = (size_t)M_ * TP2;
    float sr = 0.f, srr = 0.f, sd = 0.f, sdd = 0.f;
    for (int t = threadIdx.x; t < T_; t += 256) {
        float r = 0.f;
#pragma unroll
        for (int s = 0; s < SPLITK; s++) r += rpart[s * rstr + rbase + t];
        rsum[t] = r;
        float xv = data[dbase + t], m = mf[b * T_ + t];
        sr += r; srr += r * r; sd += xv * m; sdd += xv * xv * m;
    }
    red[threadIdx.x] = make_float4(sr, srr, sd, sdd);
    __syncthreads();
    for (int w = 128; w > 0; w >>= 1) {
        if (threadIdx.x < w) {
            float4 a = red[threadIdx.x], c = red[threadIdx.x + w];
            red[threadIdx.x] = make_float4(a.x + c.x, a.y + c.y, a.z + c.z, a.w + c.w);
        }
        __syncthreads();
    }
    if (threadIdx.x == 0) {
        float4 v = red[0];
        float cn = cnt[b];
        float varr = (v.y - v.x * v.x / (float)T_) / (float)(T_ - 1);
        float vard = (v.w - v.z * v.z / cn) / (cn - 1.f);
        s_scale = sqrtf(vard / varr);
    }
    __syncthreads();
    float scale = s_scale;
    for (int t = threadIdx.x; t < T_; t += 256) {
        float m = mf[b * T_ + t];
        out[dbase + t] = (m > 0.5f) ? data[dbase + t] : rsum[t] * scale;
    }
}

extern "C" void kernel_launch(void* const* d_in, const int* in_sizes, int n_in,
                              void* d_out, int out_size, void* d_ws, size_t ws_size,
                              hipStream_t stream) {
    const float* data = (const float*)d_in[0];
    const void* mask = d_in[1];
    float* out = (float*)d_out;

    // Replicate numpy arange length computation exactly (double precision).
    const double timespan = 1.0 * (T_ + 1) - 1.0;               // 1200
    const double fstep = 1.0 / (timespan * 8.0);                // OSFREQ = 8
    const double stop = (1.0 * (double)T_) / (2.0 * timespan) + fstep;
    const int K = (int)ceil((stop - fstep) / fstep);            // 4800 (or 4801)

    char* w = (char*)d_ws;
    auto alloc = [&](size_t nbytes) {
        char* p = w;
        w += ((nbytes + 255) / 256) * 256;
        return p;
    };
    float*     mf    = (float*)    alloc((size_t)B_ * T_ * 4);
    float*     cnt   = (float*)    alloc(B_ * 4);
    float2*    rot1  = (float2*)   alloc((size_t)KP * 8);
    float2*    rot8  = (float2*)   alloc((size_t)KP * 8);
    float2*    rot64 = (float2*)   alloc((size_t)KP * 8);
    float*     cphi  = (float*)    alloc((size_t)B_ * KP * 4);
    float*     sphi  = (float*)    alloc((size_t)B_ * KP * 4);
    float*     rdc   = (float*)    alloc((size_t)B_ * KP * 4);
    float*     rds   = (float*)    alloc((size_t)B_ * KP * 4);
    _Float16*  dm_h  = (_Float16*) alloc((size_t)M_ * TP2 * 2);
    _Float16*  Z     = (_Float16*) alloc((size_t)K2P * TP2 * 2);
    _Float16*  ZT    = (_Float16*) alloc((size_t)TP2 * K2P * 2);
    _Float16*  W     = (_Float16*) alloc((size_t)M_ * K2P * 2);
    float*     rpart = (float*)    alloc((size_t)SPLITK * M_ * TP2 * 4);
    (void)ws_size; (void)in_sizes; (void)n_in; (void)out_size;

    setup_kernel<<<20, 256, 0, stream>>>(mask, mf, cnt, rot1, rot8, rot64, fstep);
    basisC_kernel<<<162, 256, 0, stream>>>(mf, data, cnt, rot1, rot8, rot64,
                                           Z, ZT, dm_h, cphi, sphi, rdc, rds, K);
    gemm1x<<<304, 256, 0, stream>>>(dm_h, Z, cphi, sphi, rdc, rds, W);
    gemm2x<<<320, 256, 0, stream>>>(W, ZT, rpart);
    norm3_kernel<<<M_, 256, 0, stream>>>(rpart, data, mf, cnt, out);
}